// Round 25
// baseline (728.676 us; speedup 1.0000x reference)
//
#include <hip/hip_runtime.h>
#include <hip/hip_bf16.h>
#include <math.h>

#define CC_COST 0.25

typedef __attribute__((ext_vector_type(8))) short short8v;
typedef __attribute__((ext_vector_type(4))) float f32x4;
typedef __attribute__((ext_vector_type(16))) float f32x16;

__device__ __forceinline__ unsigned short f2bf(float f) {
    unsigned u = __float_as_uint(f);
    unsigned r = (u + 0x7FFFu + ((u >> 16) & 1u)) >> 16;
    return (unsigned short)r;
}
__device__ __forceinline__ float bf2f(unsigned short h) {
    return __uint_as_float(((unsigned)h) << 16);
}

// ===========================================================================
// VQ-VAE forward. All heavy convs + VQ GEMM on MFMA (bf16 hi/lo 3-product).
// Res blocks fully fused; upconv on MFMA; VQ split into dist+argmin kernel
// and a streaming gather/loss kernel.
// d_out[0]=loss, [1..]=recon, [last]=perplexity
// ===========================================================================

// ---------------- batched weight transforms (fp32 vector kernels) ----------
struct WtJobs {
    const float* src[15];
    float* dst[15];
    int cout[15], cin[15], kk[15], kind[15];
    int blk0[16];
};

__global__ void wt_batch_k(WtJobs J)
{
    int blk = blockIdx.x;
    int j = 0;
    while (j < 14 && blk >= J.blk0[j + 1]) ++j;
    int i = (blk - J.blk0[j]) * 256 + threadIdx.x;
    int total = J.cout[j] * J.cin[j] * J.kk[j];
    if (i >= total) return;
    const float* src = J.src[j];
    float* dst = J.dst[j];
    int kind = J.kind[j];
    if (kind == 0) {
        int Cout = J.cout[j], Cin = J.cin[j], KK = J.kk[j];
        int oc = i % Cout; int t2 = i / Cout; int t = t2 % KK; int c = t2 / KK;
        dst[i] = src[(oc * Cin + c) * KK + t];
    } else {
        int o = i % 3; int t = (i / 3) % 9; int c = i / 27;
        dst[i] = src[(o * 64 + c) * 9 + t];
    }
}

// split OIHW [128][128][3][3] fp32 -> whi/wlo bf16 in [9 tap][8 cb][128 oc][16 ci]
__global__ void wt_split_k(const float* __restrict__ w,
                           unsigned short* __restrict__ whi,
                           unsigned short* __restrict__ wlo)
{
    int i = blockIdx.x * 256 + threadIdx.x;
    if (i >= 147456) return;
    int ci = i & 15;
    int oc = (i >> 4) & 127;
    int rest = i >> 11;           // 0..71
    int cb = rest & 7;
    int tap = rest >> 3;          // 0..8
    float v = w[(oc * 128 + cb * 16 + ci) * 9 + tap];
    unsigned short h = f2bf(v);
    whi[i] = h;
    wlo[i] = f2bf(v - bf2f(h));
}

// split enc_c2 OIHW [128][64][4][4] -> [16 tap][4 cb][128 oc][16 ci] hi/lo
__global__ void wt_split4_k(const float* __restrict__ w,
                            unsigned short* __restrict__ whi,
                            unsigned short* __restrict__ wlo)
{
    int i = blockIdx.x * 256 + threadIdx.x;
    if (i >= 131072) return;
    int t = i & 15;
    int oc = (i >> 4) & 127;
    int rest = i >> 11;           // 0..63
    int cb = rest & 3;
    int tap = rest >> 2;          // 0..15
    float v = w[(oc * 64 + cb * 16 + t) * 16 + tap];
    unsigned short h = f2bf(v);
    whi[i] = h;
    wlo[i] = f2bf(v - bf2f(h));
}

// split dec_dc [128 cin][64 oc][4 ky][4 kx] -> [ky4][kx4][cb8][64 oc][16 ci] hi/lo
__global__ void wt_split_dc_k(const float* __restrict__ w,
                              unsigned short* __restrict__ whi,
                              unsigned short* __restrict__ wlo)
{
    int i = blockIdx.x * 256 + threadIdx.x;
    if (i >= 131072) return;
    int ci = i & 15;
    int oc = (i >> 4) & 63;
    int cb = (i >> 10) & 7;
    int kx = (i >> 13) & 3;
    int ky = i >> 15;
    float v = w[((size_t)(cb * 16 + ci) * 64 + oc) * 16 + ky * 4 + kx];
    unsigned short h = f2bf(v);
    whi[i] = h;
    wlo[i] = f2bf(v - bf2f(h));
}

// split res conv3x3 OIHW [32][128][3][3] -> [9 tap][4 cb][32 oc][32 k] hi/lo
__global__ void wt_split_r_k(const float* __restrict__ w,
                             unsigned short* __restrict__ whi,
                             unsigned short* __restrict__ wlo)
{
    int i = blockIdx.x * 256 + threadIdx.x;
    if (i >= 36864) return;
    int k5 = i & 31;
    int oc = (i >> 5) & 31;
    int cb = (i >> 10) & 3;
    int tap = i >> 12;            // 0..8
    float v = w[(oc * 128 + cb * 32 + k5) * 9 + tap];
    unsigned short h = f2bf(v);
    whi[i] = h;
    wlo[i] = f2bf(v - bf2f(h));
}

// split res conv1x1 [128 out][32 in] -> [2 kk][128 oc][16 ci] hi/lo
__global__ void wt_split_1x1_k(const float* __restrict__ w,
                               unsigned short* __restrict__ whi,
                               unsigned short* __restrict__ wlo)
{
    int i = blockIdx.x * 256 + threadIdx.x;
    if (i >= 4096) return;
    int ci = i & 15;
    int oc = (i >> 4) & 127;
    int kk = i >> 11;
    float v = w[oc * 32 + kk * 16 + ci];
    unsigned short h = f2bf(v);
    whi[i] = h;
    wlo[i] = f2bf(v - bf2f(h));
}

// split dec_c3 [3][64][3][3] -> [9 tap][4 cb][32 oc(3 used)][16 ci] hi/lo
__global__ void wt_split_up_k(const float* __restrict__ w,
                              unsigned short* __restrict__ whi,
                              unsigned short* __restrict__ wlo)
{
    int i = blockIdx.x * 256 + threadIdx.x;
    if (i >= 18432) return;
    int ci = i & 15;
    int oc = (i >> 4) & 31;
    int cb = (i >> 9) & 3;
    int tap = i >> 11;            // 0..8
    float v = 0.f;
    if (oc < 3) {
        int ch = cb * 16 + ci;
        v = w[(oc * 64 + ch) * 9 + tap];
    }
    unsigned short h = f2bf(v);
    whi[i] = h;
    wlo[i] = f2bf(v - bf2f(h));
}

// ---------------- MFMA conv3x3 s1 p1, 128->128, 64x64, batch 8 -------------
__global__ __launch_bounds__(512) void conv3x3_mfma(
    const float* __restrict__ in,           // [8,128,64,64]
    const unsigned short* __restrict__ whi, // [9][8][128][16] bf16
    const unsigned short* __restrict__ wlo,
    float* __restrict__ out)                // [8,128,64,64]
{
    constexpr int CST = 40;
    __shared__ unsigned short ls_hi[4 * 68 * CST];
    __shared__ unsigned short ls_lo[4 * 68 * CST];

    int tid = threadIdx.x;
    int lane = tid & 63;
    int w = tid >> 6;
    int myrow = w & 1;
    int oc0 = (w >> 1) * 32;
    int y0 = (blockIdx.x & 31) * 2;
    int b  = blockIdx.x >> 5;
    int ln31 = lane & 31;
    int lhf  = lane >> 5;

    f32x16 acc0 = {};
    f32x16 acc1 = {};

    const float* inb = in + (size_t)b * 128 * 4096;

    for (int chunk = 0; chunk < 4; ++chunk) {
        int c0 = chunk * 32;
        __syncthreads();
        for (int i = tid; i < 4 * 66 * 16; i += 512) {
            int x = i % 66;
            int t = i / 66;
            int cp = t & 15;
            int r = t >> 4;
            int gy = y0 - 1 + r, gx = x - 1;
            float v0 = 0.f, v1 = 0.f;
            if ((unsigned)gy < 64u && (unsigned)gx < 64u) {
                const float* p = inb + (size_t)(c0 + 2 * cp) * 4096 + gy * 64 + gx;
                v0 = p[0];
                v1 = p[4096];
            }
            unsigned short h0 = f2bf(v0), h1 = f2bf(v1);
            unsigned short l0 = f2bf(v0 - bf2f(h0)), l1 = f2bf(v1 - bf2f(h1));
            int a = (r * 68 + x) * CST + 2 * cp;
            *reinterpret_cast<unsigned int*>(&ls_hi[a]) = (unsigned)h0 | ((unsigned)h1 << 16);
            *reinterpret_cast<unsigned int*>(&ls_lo[a]) = (unsigned)l0 | ((unsigned)l1 << 16);
        }
        __syncthreads();

        #pragma unroll
        for (int tap = 0; tap < 9; ++tap) {
            int dy = tap / 3, dx = tap - 3 * (tap / 3);
            int rbase = (myrow + dy) * 68;
            #pragma unroll
            for (int cb = 0; cb < 2; ++cb) {
                int cbg = chunk * 2 + cb;
                size_t wofs = (((size_t)tap * 8 + cbg) * 128 + oc0 + ln31) * 16 + lhf * 8;
                short8v ah = *reinterpret_cast<const short8v*>(whi + wofs);
                short8v al = *reinterpret_cast<const short8v*>(wlo + wofs);
                int k0 = cb * 16 + lhf * 8;
                int xo0 = (rbase + ln31 + dx) * CST + k0;
                int xo1 = (rbase + 32 + ln31 + dx) * CST + k0;
                short8v bh0 = *reinterpret_cast<const short8v*>(&ls_hi[xo0]);
                short8v bl0 = *reinterpret_cast<const short8v*>(&ls_lo[xo0]);
                short8v bh1 = *reinterpret_cast<const short8v*>(&ls_hi[xo1]);
                short8v bl1 = *reinterpret_cast<const short8v*>(&ls_lo[xo1]);
                acc0 = __builtin_amdgcn_mfma_f32_32x32x16_bf16(ah, bh0, acc0, 0, 0, 0);
                acc1 = __builtin_amdgcn_mfma_f32_32x32x16_bf16(ah, bh1, acc1, 0, 0, 0);
                acc0 = __builtin_amdgcn_mfma_f32_32x32x16_bf16(ah, bl0, acc0, 0, 0, 0);
                acc1 = __builtin_amdgcn_mfma_f32_32x32x16_bf16(ah, bl1, acc1, 0, 0, 0);
                acc0 = __builtin_amdgcn_mfma_f32_32x32x16_bf16(al, bh0, acc0, 0, 0, 0);
                acc1 = __builtin_amdgcn_mfma_f32_32x32x16_bf16(al, bh1, acc1, 0, 0, 0);
            }
        }
    }

    float* ob = out + (size_t)b * 128 * 4096 + (size_t)(y0 + myrow) * 64;
    #pragma unroll
    for (int r = 0; r < 16; ++r) {
        int oc = oc0 + (r & 3) + 8 * (r >> 2) + 4 * lhf;
        ob[(size_t)oc * 4096 + ln31]      = acc0[r];
        ob[(size_t)oc * 4096 + 32 + ln31] = acc1[r];
    }
}

// ---------------- MFMA conv4x4 s2 p1, 64->128, in 128x128 -> out 64x64 -----
__global__ __launch_bounds__(512) void conv4x4s2_mfma(
    const float* __restrict__ in,            // [8,64,128,128] post-relu
    const unsigned short* __restrict__ whi,  // [16 tap][4 cb][128 oc][16 ci]
    const unsigned short* __restrict__ wlo,
    float* __restrict__ out)                 // [8,128,64,64], relu out
{
    constexpr int CST = 24;                  // 16 ci + 8 pad (48B = 16B-aligned)
    __shared__ unsigned short lsEh[6 * 65 * CST];
    __shared__ unsigned short lsEl[6 * 65 * CST];
    __shared__ unsigned short lsOh[6 * 65 * CST];
    __shared__ unsigned short lsOl[6 * 65 * CST];

    int tid = threadIdx.x;
    int lane = tid & 63;
    int w = tid >> 6;
    int myrow = w & 1;
    int oc0 = (w >> 1) * 32;
    int y0 = (blockIdx.x & 31) * 2;
    int b  = blockIdx.x >> 5;
    int ln31 = lane & 31;
    int lhf  = lane >> 5;

    f32x16 acc0 = {};
    f32x16 acc1 = {};

    const float* inb = in + (size_t)b * 64 * 16384;

    for (int cb = 0; cb < 4; ++cb) {
        int c0 = cb * 16;
        __syncthreads();
        for (int i = tid; i < 12480; i += 512) {
            int gxi = i % 130; int t2 = i / 130;
            int r = t2 % 6; int cc = t2 / 6;
            int gx = gxi - 1;
            int gy = 2 * y0 - 1 + r;
            float v = 0.f;
            if ((unsigned)gy < 128u && (unsigned)gx < 128u)
                v = inb[(size_t)(c0 + cc) * 16384 + gy * 128 + gx];
            unsigned short h = f2bf(v);
            unsigned short l = f2bf(v - bf2f(h));
            if (gx & 1) {
                int a = (r * 65 + ((gx + 1) >> 1)) * CST + cc;
                lsOh[a] = h; lsOl[a] = l;
            } else {
                int a = (r * 65 + (gx >> 1)) * CST + cc;
                lsEh[a] = h; lsEl[a] = l;
            }
        }
        __syncthreads();

        #pragma unroll
        for (int tap = 0; tap < 16; ++tap) {
            int ky = tap >> 2, kx = tap & 3;
            int ridx = 2 * myrow + ky;
            int dlt = kx >> 1;
            const unsigned short* ph = (kx & 1) ? lsEh : lsOh;
            const unsigned short* pl = (kx & 1) ? lsEl : lsOl;
            size_t aoff = ((size_t)((tap * 4 + cb) * 128 + oc0 + ln31)) * 16 + lhf * 8;
            short8v ah = *reinterpret_cast<const short8v*>(whi + aoff);
            short8v al = *reinterpret_cast<const short8v*>(wlo + aoff);
            int base0 = (ridx * 65 + ln31 + dlt) * CST + lhf * 8;
            int base1 = (ridx * 65 + 32 + ln31 + dlt) * CST + lhf * 8;
            short8v bh0 = *reinterpret_cast<const short8v*>(ph + base0);
            short8v bl0 = *reinterpret_cast<const short8v*>(pl + base0);
            short8v bh1 = *reinterpret_cast<const short8v*>(ph + base1);
            short8v bl1 = *reinterpret_cast<const short8v*>(pl + base1);
            acc0 = __builtin_amdgcn_mfma_f32_32x32x16_bf16(ah, bh0, acc0, 0, 0, 0);
            acc1 = __builtin_amdgcn_mfma_f32_32x32x16_bf16(ah, bh1, acc1, 0, 0, 0);
            acc0 = __builtin_amdgcn_mfma_f32_32x32x16_bf16(ah, bl0, acc0, 0, 0, 0);
            acc1 = __builtin_amdgcn_mfma_f32_32x32x16_bf16(ah, bl1, acc1, 0, 0, 0);
            acc0 = __builtin_amdgcn_mfma_f32_32x32x16_bf16(al, bh0, acc0, 0, 0, 0);
            acc1 = __builtin_amdgcn_mfma_f32_32x32x16_bf16(al, bh1, acc1, 0, 0, 0);
        }
    }

    int y = y0 + myrow;
    float* ob = out + (size_t)b * 128 * 4096 + (size_t)y * 64;
    #pragma unroll
    for (int r = 0; r < 16; ++r) {
        int oc = oc0 + (r & 3) + 8 * (r >> 2) + 4 * lhf;
        ob[(size_t)oc * 4096 + ln31]      = fmaxf(acc0[r], 0.f);
        ob[(size_t)oc * 4096 + 32 + ln31] = fmaxf(acc1[r], 0.f);
    }
}

// ---------------- MFMA deconv 4x4 s2 p1, 128->64, relu(in), relu(out) ------
__global__ __launch_bounds__(512) void deconv_mfma(
    const float* __restrict__ in,            // [8,128,64,64] pre-relu
    const unsigned short* __restrict__ whi,  // [ky4][kx4][cb8][64 oc][16 ci]
    const unsigned short* __restrict__ wlo,
    float* __restrict__ out)                 // [8,64,128,128] relu
{
    constexpr int CST = 40;
    __shared__ unsigned short ls_hi[3 * 68 * CST];
    __shared__ unsigned short ls_lo[3 * 68 * CST];

    int tid = threadIdx.x;
    int lane = tid & 63;
    int w = tid >> 6;
    int myrow = w & 1;                 // output row oy = 2*yb + myrow
    int oc0 = ((w >> 1) & 1) * 32;     // oc tile
    int oxp = w >> 2;                  // ox parity (0 even, 1 odd)
    int yb = blockIdx.x & 63;
    int b  = blockIdx.x >> 6;
    int ln31 = lane & 31;
    int lhf  = lane >> 5;

    f32x16 acc0 = {};
    f32x16 acc1 = {};

    const float* inb = in + (size_t)b * 128 * 4096;

    for (int chunk = 0; chunk < 4; ++chunk) {
        int c0 = chunk * 32;
        __syncthreads();
        for (int i = tid; i < 3 * 66 * 16; i += 512) {
            int x = i % 66;
            int t = i / 66;
            int cp = t & 15;
            int r = t >> 4;            // 0..2
            int gy = yb - 1 + r, gx = x - 1;
            float v0 = 0.f, v1 = 0.f;
            if ((unsigned)gy < 64u && (unsigned)gx < 64u) {
                const float* p = inb + (size_t)(c0 + 2 * cp) * 4096 + gy * 64 + gx;
                v0 = fmaxf(p[0], 0.f);
                v1 = fmaxf(p[4096], 0.f);
            }
            unsigned short h0 = f2bf(v0), h1 = f2bf(v1);
            unsigned short l0 = f2bf(v0 - bf2f(h0)), l1 = f2bf(v1 - bf2f(h1));
            int a = (r * 68 + x) * CST + 2 * cp;
            *reinterpret_cast<unsigned int*>(&ls_hi[a]) = (unsigned)h0 | ((unsigned)h1 << 16);
            *reinterpret_cast<unsigned int*>(&ls_lo[a]) = (unsigned)l0 | ((unsigned)l1 << 16);
        }
        __syncthreads();

        #pragma unroll
        for (int tki = 0; tki < 2; ++tki) {
            int ky = (1 - myrow) + 2 * tki;
            int ldsrow = 1 + myrow - tki;
            #pragma unroll
            for (int txi = 0; txi < 2; ++txi) {
                int kx = (1 - oxp) + 2 * txi;
                int dlt = oxp - txi;           // ix = dlt + lane index
                #pragma unroll
                for (int cb = 0; cb < 2; ++cb) {
                    int cbg = chunk * 2 + cb;
                    size_t aoff = ((size_t)(((ky * 4 + kx) * 8 + cbg) * 64 + oc0 + ln31)) * 16 + lhf * 8;
                    short8v ah = *reinterpret_cast<const short8v*>(whi + aoff);
                    short8v al = *reinterpret_cast<const short8v*>(wlo + aoff);
                    int k0 = cb * 16 + lhf * 8;
                    int xo0 = (ldsrow * 68 + ln31 + dlt + 1) * CST + k0;
                    int xo1 = (ldsrow * 68 + 32 + ln31 + dlt + 1) * CST + k0;
                    short8v bh0 = *reinterpret_cast<const short8v*>(&ls_hi[xo0]);
                    short8v bl0 = *reinterpret_cast<const short8v*>(&ls_lo[xo0]);
                    short8v bh1 = *reinterpret_cast<const short8v*>(&ls_hi[xo1]);
                    short8v bl1 = *reinterpret_cast<const short8v*>(&ls_lo[xo1]);
                    acc0 = __builtin_amdgcn_mfma_f32_32x32x16_bf16(ah, bh0, acc0, 0, 0, 0);
                    acc1 = __builtin_amdgcn_mfma_f32_32x32x16_bf16(ah, bh1, acc1, 0, 0, 0);
                    acc0 = __builtin_amdgcn_mfma_f32_32x32x16_bf16(ah, bl0, acc0, 0, 0, 0);
                    acc1 = __builtin_amdgcn_mfma_f32_32x32x16_bf16(ah, bl1, acc1, 0, 0, 0);
                    acc0 = __builtin_amdgcn_mfma_f32_32x32x16_bf16(al, bh0, acc0, 0, 0, 0);
                    acc1 = __builtin_amdgcn_mfma_f32_32x32x16_bf16(al, bh1, acc1, 0, 0, 0);
                }
            }
        }
    }

    int oy = 2 * yb + myrow;
    float* ob = out + (size_t)b * 64 * 16384 + (size_t)oy * 128;
    #pragma unroll
    for (int r = 0; r < 16; ++r) {
        int oc = oc0 + (r & 3) + 8 * (r >> 2) + 4 * lhf;
        ob[(size_t)oc * 16384 + oxp + 2 * ln31]      = fmaxf(acc0[r], 0.f);
        ob[(size_t)oc * 16384 + oxp + 64 + 2 * ln31] = fmaxf(acc1[r], 0.f);
    }
}

// ---------------- fused res block: conv3x3 128->32 + relu + 1x1 32->128 + res
__global__ __launch_bounds__(512) void fused_res_k(
    const float* __restrict__ in,            // [8,128,64,64] pre-relu (+res)
    const unsigned short* __restrict__ whi,  // 3x3 [9][4][32 oc][32 k]
    const unsigned short* __restrict__ wlo,
    const unsigned short* __restrict__ w1hi, // 1x1 [2 kk][128 oc][16 ci]
    const unsigned short* __restrict__ w1lo,
    float* __restrict__ out)                 // [8,128,64,64]
{
    constexpr int CST = 40;
    __shared__ unsigned short ls_hi[3 * 68 * CST];
    __shared__ unsigned short ls_lo[3 * 68 * CST];

    int tid = threadIdx.x;
    int lane = tid & 63;
    int w = tid >> 6;
    int oc0 = (w & 1) * 16;
    int px0 = (w >> 1) * 16;
    int y = blockIdx.x & 63;
    int b = blockIdx.x >> 6;
    int n16 = lane & 15;
    int kk4 = lane >> 4;
    int ln31 = lane & 31;
    int lhf = lane >> 5;

    f32x4 acc = {};
    const float* inb = in + (size_t)b * 128 * 4096;

    for (int cb = 0; cb < 4; ++cb) {
        int c0 = cb * 32;
        __syncthreads();
        for (int i = tid; i < 3 * 66 * 16; i += 512) {
            int x = i % 66;
            int t = i / 66;
            int cp = t & 15;
            int r = t >> 4;            // 0..2
            int gy = y - 1 + r, gx = x - 1;
            float v0 = 0.f, v1 = 0.f;
            if ((unsigned)gy < 64u && (unsigned)gx < 64u) {
                const float* p = inb + (size_t)(c0 + 2 * cp) * 4096 + gy * 64 + gx;
                v0 = fmaxf(p[0], 0.f);
                v1 = fmaxf(p[4096], 0.f);
            }
            unsigned short h0 = f2bf(v0), h1 = f2bf(v1);
            unsigned short l0 = f2bf(v0 - bf2f(h0)), l1 = f2bf(v1 - bf2f(h1));
            int a = (r * 68 + x) * CST + 2 * cp;
            *reinterpret_cast<unsigned int*>(&ls_hi[a]) = (unsigned)h0 | ((unsigned)h1 << 16);
            *reinterpret_cast<unsigned int*>(&ls_lo[a]) = (unsigned)l0 | ((unsigned)l1 << 16);
        }
        __syncthreads();

        #pragma unroll
        for (int tap = 0; tap < 9; ++tap) {
            int dy = tap / 3, dx = tap - 3 * (tap / 3);
            size_t aoff = ((size_t)((tap * 4 + cb) * 32 + oc0 + n16)) * 32 + kk4 * 8;
            short8v ah = *reinterpret_cast<const short8v*>(whi + aoff);
            short8v al = *reinterpret_cast<const short8v*>(wlo + aoff);
            int xo = (dy * 68 + px0 + n16 + dx) * CST + kk4 * 8;
            short8v bh = *reinterpret_cast<const short8v*>(&ls_hi[xo]);
            short8v bl = *reinterpret_cast<const short8v*>(&ls_lo[xo]);
            acc = __builtin_amdgcn_mfma_f32_16x16x32_bf16(ah, bh, acc, 0, 0, 0);
            acc = __builtin_amdgcn_mfma_f32_16x16x32_bf16(ah, bl, acc, 0, 0, 0);
            acc = __builtin_amdgcn_mfma_f32_16x16x32_bf16(al, bh, acc, 0, 0, 0);
        }
    }

    // phase B: relu(P) -> LDS [px][ch] hi/lo (overlay on staging buffers)
    __syncthreads();
    #pragma unroll
    for (int r = 0; r < 4; ++r) {
        int ch = oc0 + kk4 * 4 + r;        // C layout: row=(lane>>4)*4+r
        int px = px0 + n16;                // col = lane&15
        float v = fmaxf(acc[r], 0.f);
        unsigned short h = f2bf(v);
        ls_hi[px * CST + ch] = h;
        ls_lo[px * CST + ch] = f2bf(v - bf2f(h));
    }
    __syncthreads();

    // phase C: 1x1 GEMM 32->128 (2 kk x 3 MFMA 32x32x16)
    int oc1 = (w & 3) * 32;
    int pxt = (w >> 2) * 32;
    f32x16 acc2 = {};
    #pragma unroll
    for (int kk = 0; kk < 2; ++kk) {
        size_t aoff = ((size_t)(kk * 128 + oc1 + ln31)) * 16 + lhf * 8;
        short8v ah = *reinterpret_cast<const short8v*>(w1hi + aoff);
        short8v al = *reinterpret_cast<const short8v*>(w1lo + aoff);
        int boff = (pxt + ln31) * CST + kk * 16 + lhf * 8;
        short8v bh = *reinterpret_cast<const short8v*>(&ls_hi[boff]);
        short8v bl = *reinterpret_cast<const short8v*>(&ls_lo[boff]);
        acc2 = __builtin_amdgcn_mfma_f32_32x32x16_bf16(ah, bh, acc2, 0, 0, 0);
        acc2 = __builtin_amdgcn_mfma_f32_32x32x16_bf16(ah, bl, acc2, 0, 0, 0);
        acc2 = __builtin_amdgcn_mfma_f32_32x32x16_bf16(al, bh, acc2, 0, 0, 0);
    }

    // phase D: residual add (fp32) + store
    float* ob = out + (size_t)b * 128 * 4096 + (size_t)y * 64;
    const float* rb = inb + (size_t)y * 64;
    #pragma unroll
    for (int r = 0; r < 16; ++r) {
        int oc = oc1 + (r & 3) + 8 * (r >> 2) + 4 * lhf;
        size_t o = (size_t)oc * 4096 + pxt + ln31;
        ob[o] = rb[o] + acc2[r];
    }
}

// ---------------- conv 1x1 on 64x64 (COUT must be 128) ----------------
template<int CIN, int COUT, int CC, bool IN_RELU, bool ADD_RES>
__global__ __launch_bounds__(256) void conv1x1_k(
    const float* __restrict__ in, const float* __restrict__ wT,
    const float* __restrict__ res, float* __restrict__ out)
{
    static_assert(COUT == 128, "tile assumes 128");
    __shared__ __align__(16) float ls_in[CC][64];
    __shared__ __align__(16) float ls_w[CC][COUT];
    int tid = threadIdx.x;
    int pxg = tid & 7, ocg = tid >> 3;
    int x0 = pxg * 8, oc0 = ocg * 4;
    int y = blockIdx.x & 63, b = blockIdx.x >> 6;

    float acc[4][8];
    #pragma unroll
    for (int o = 0; o < 4; ++o)
        #pragma unroll
        for (int p = 0; p < 8; ++p) acc[o][p] = 0.f;

    for (int c0 = 0; c0 < CIN; c0 += CC) {
        __syncthreads();
        for (int i = tid; i < CC * 64; i += 256) {
            int xx = i & 63, cc = i >> 6;
            float v = in[(((size_t)b * CIN + c0 + cc) * 64 + y) * 64 + xx];
            if (IN_RELU) v = fmaxf(v, 0.f);
            ls_in[cc][xx] = v;
        }
        const float* wsrc = wT + (size_t)c0 * COUT;
        for (int i = tid; i < CC * COUT; i += 256)
            (&ls_w[0][0])[i] = wsrc[i];
        __syncthreads();

        for (int cc = 0; cc < CC; ++cc) {
            float rv[8];
            const float* base = &ls_in[cc][x0];
            float4 v0 = *reinterpret_cast<const float4*>(base);
            float4 v1 = *reinterpret_cast<const float4*>(base + 4);
            rv[0]=v0.x; rv[1]=v0.y; rv[2]=v0.z; rv[3]=v0.w;
            rv[4]=v1.x; rv[5]=v1.y; rv[6]=v1.z; rv[7]=v1.w;
            float4 w4 = *reinterpret_cast<const float4*>(&ls_w[cc][oc0]);
            float wv[4] = {w4.x, w4.y, w4.z, w4.w};
            #pragma unroll
            for (int p = 0; p < 8; ++p)
                #pragma unroll
                for (int o = 0; o < 4; ++o)
                    acc[o][p] = fmaf(rv[p], wv[o], acc[o][p]);
        }
    }
    #pragma unroll
    for (int o = 0; o < 4; ++o) {
        float* op = out + (((size_t)b * COUT + oc0 + o) * 64 + y) * 64 + x0;
        const float* rp = res + (((size_t)b * COUT + oc0 + o) * 64 + y) * 64 + x0;
        #pragma unroll
        for (int q = 0; q < 2; ++q) {
            float4 v = make_float4(acc[o][4*q], acc[o][4*q+1],
                                   acc[o][4*q+2], acc[o][4*q+3]);
            if (ADD_RES) {
                float4 r4 = *reinterpret_cast<const float4*>(rp + 4 * q);
                v.x += r4.x; v.y += r4.y; v.z += r4.z; v.w += r4.w;
            }
            *reinterpret_cast<float4*>(op + 4 * q) = v;
        }
    }
}

// ---------------- conv 4x4 s2 p1 (vector; used for enc_c1 3->64) -----------
template<int CIN, int COUT, int WOUT, int CC, int OCB, int WOC, int NSLICE>
__global__ __launch_bounds__(256) void conv4x4s2_k(
    const float* __restrict__ in, const float* __restrict__ wT,
    float* __restrict__ out)
{
    constexpr int WIN = WOUT * 2;
    constexpr int NPXG = WOUT / 8, NOCG = COUT / OCB;
    static_assert(NPXG * NOCG == 256, "bad tile");
    constexpr int WUSE = 2 * WOUT + 2;
    constexpr int PADLEN = ((WUSE + (WUSE / 16 + 1) * 4) + 3) & ~3;
    __shared__ __align__(16) float ls_in[CC][4][PADLEN];
    __shared__ __align__(16) float ls_w[CC][16][COUT];

    int tid = threadIdx.x;
    int pxg = tid % NPXG, ocg = tid / NPXG;
    int x0 = pxg * 8, oc0 = ocg * OCB;
    int blk = blockIdx.x;
    int y = blk % WOUT; int rest = blk / WOUT;
    int slice = rest % NSLICE; int b = rest / NSLICE;
    int oc_base = slice * COUT;
    const float* inb = in + (size_t)b * CIN * WIN * WIN;

    float acc[OCB][8];
    #pragma unroll
    for (int o = 0; o < OCB; ++o)
        #pragma unroll
        for (int p = 0; p < 8; ++p) acc[o][p] = 0.f;

    for (int c0 = 0; c0 < CIN; c0 += CC) {
        __syncthreads();
        for (int i = tid; i < CC * 4 * WUSE; i += 256) {
            int xx = i % WUSE; int t = i / WUSE; int r = t & 3; int cc = t >> 2;
            int gy = 2 * y - 1 + r, gx = xx - 1;
            float v = 0.f;
            if ((unsigned)gy < (unsigned)WIN && (unsigned)gx < (unsigned)WIN)
                v = inb[(c0 + cc) * WIN * WIN + gy * WIN + gx];
            ls_in[cc][r][xx + ((xx >> 4) << 2)] = v;
        }
        const float* wsrc = wT + (size_t)c0 * 16 * WOC + oc_base;
        for (int i = tid; i < CC * 16 * COUT; i += 256) {
            int o = i % COUT; int tt = (i / COUT) % 16; int cc = i / (16 * COUT);
            ls_w[cc][tt][o] = wsrc[(cc * 16 + tt) * WOC + o];
        }
        __syncthreads();

        for (int cc = 0; cc < CC; ++cc) {
            const float* lw = &ls_w[cc][0][0];
            #pragma unroll
            for (int ky = 0; ky < 4; ++ky) {
                float rv[18];
                const float* base = &ls_in[cc][ky][20 * pxg];
                #pragma unroll
                for (int q = 0; q < 4; ++q) {
                    float4 v = *reinterpret_cast<const float4*>(base + 4 * q);
                    rv[4*q]=v.x; rv[4*q+1]=v.y; rv[4*q+2]=v.z; rv[4*q+3]=v.w;
                }
                rv[16] = base[20]; rv[17] = base[21];
                #pragma unroll
                for (int kx = 0; kx < 4; ++kx) {
                    const float* wp = lw + (ky * 4 + kx) * COUT + oc0;
                    float wv[OCB];
                    if constexpr (OCB == 4) {
                        float4 w4 = *reinterpret_cast<const float4*>(wp);
                        wv[0]=w4.x; wv[1]=w4.y; wv[2]=w4.z; wv[3]=w4.w;
                    } else {
                        float2 w2 = *reinterpret_cast<const float2*>(wp);
                        wv[0]=w2.x; wv[1]=w2.y;
                    }
                    #pragma unroll
                    for (int p = 0; p < 8; ++p) {
                        float iv = rv[2 * p + kx];
                        #pragma unroll
                        for (int o = 0; o < OCB; ++o)
                            acc[o][p] = fmaf(iv, wv[o], acc[o][p]);
                    }
                }
            }
        }
    }
    #pragma unroll
    for (int o = 0; o < OCB; ++o) {
        float* op = out + (((size_t)b * (COUT * NSLICE) + oc_base + oc0 + o) * WOUT + y) * WOUT + x0;
        #pragma unroll
        for (int q = 0; q < 2; ++q) {
            float4 v = make_float4(fmaxf(acc[o][4*q],0.f), fmaxf(acc[o][4*q+1],0.f),
                                   fmaxf(acc[o][4*q+2],0.f), fmaxf(acc[o][4*q+3],0.f));
            *reinterpret_cast<float4*>(op + 4 * q) = v;
        }
    }
}

// ---------------- MFMA upconv: bilinear-2x(align) + conv3x3 64->3 + sigmoid -
__global__ __launch_bounds__(512) void upconv_mfma(
    const float* __restrict__ in,            // [8,64,128,128] post-relu
    const unsigned short* __restrict__ whi,
    const unsigned short* __restrict__ wlo,
    float* __restrict__ out)                 // [8,3,256,256]
{
    constexpr int CST = 24;
    __shared__ unsigned short ls_hi[6 * 68 * CST];
    __shared__ unsigned short ls_lo[6 * 68 * CST];
    __shared__ float xfx[68];
    __shared__ int   xloT[68];

    int tid = threadIdx.x;
    int lane = tid & 63;
    int w = tid >> 6;
    int myrow = w & 3;                 // output row within block
    int pt = w >> 2;                   // px tile: 0/1 -> px base pt*32
    int blk = blockIdx.x;
    int xq = blk & 3;
    int yblk = (blk >> 2) & 63;
    int b = blk >> 8;
    int xbase = xq * 64;
    int y0 = yblk * 4;
    int ln31 = lane & 31;
    int lhf = lane >> 5;
    const float SCL = 127.0f / 255.0f;
    const float* hb = in + (size_t)b * 64 * 16384;

    if (tid < 68) {
        int ux = xbase - 1 + tid;
        bool v = ((unsigned)ux < 256u);
        float px = (v ? ux : 0) * SCL;
        int lo = (int)px;
        xloT[tid] = lo;
        xfx[tid] = v ? (px - (float)lo) : -1.0f;   // -1 marks OOB
    }

    f32x16 acc = {};

    for (int chunk = 0; chunk < 4; ++chunk) {
        int c0 = chunk * 16;
        __syncthreads();
        for (int i = tid; i < 6 * 68 * 8; i += 512) {
            int xx = i % 68; int t = i / 68; int cp = t & 7; int r = t >> 3;
            int uy = y0 - 1 + r;
            float v0 = 0.f, v1 = 0.f;
            float fx = xfx[xx];
            if ((unsigned)uy < 256u && fx >= 0.f) {
                float py = uy * SCL;
                int ylo = (int)py; int yhi = min(ylo + 1, 127);
                float fy = py - (float)ylo;
                int lo = xloT[xx]; int hi = min(lo + 1, 127);
                const float* hp = hb + (size_t)(c0 + 2 * cp) * 16384;
                const float* p0 = hp + ylo * 128;
                const float* p1 = hp + yhi * 128;
                float a = p0[lo], b2 = p0[hi], c2 = p1[lo], d2 = p1[hi];
                float top = a + (b2 - a) * fx;
                float bot = c2 + (d2 - c2) * fx;
                v0 = top + (bot - top) * fy;
                const float* q0 = p0 + 16384;
                const float* q1 = p1 + 16384;
                float a2 = q0[lo], b3 = q0[hi], c3 = q1[lo], d3 = q1[hi];
                float top2 = a2 + (b3 - a2) * fx;
                float bot2 = c3 + (d3 - c3) * fx;
                v1 = top2 + (bot2 - top2) * fy;
            }
            unsigned short h0 = f2bf(v0), h1 = f2bf(v1);
            unsigned short l0 = f2bf(v0 - bf2f(h0)), l1 = f2bf(v1 - bf2f(h1));
            int a = (r * 68 + xx) * CST + 2 * cp;
            *reinterpret_cast<unsigned int*>(&ls_hi[a]) = (unsigned)h0 | ((unsigned)h1 << 16);
            *reinterpret_cast<unsigned int*>(&ls_lo[a]) = (unsigned)l0 | ((unsigned)l1 << 16);
        }
        __syncthreads();

        #pragma unroll
        for (int tap = 0; tap < 9; ++tap) {
            int dy = tap / 3, dx = tap - 3 * (tap / 3);
            size_t aoff = ((size_t)((tap * 4 + chunk) * 32 + ln31)) * 16 + lhf * 8;
            short8v ah = *reinterpret_cast<const short8v*>(whi + aoff);
            short8v al = *reinterpret_cast<const short8v*>(wlo + aoff);
            int boff = ((myrow + dy) * 68 + pt * 32 + ln31 + dx) * CST + lhf * 8;
            short8v bh = *reinterpret_cast<const short8v*>(&ls_hi[boff]);
            short8v bl = *reinterpret_cast<const short8v*>(&ls_lo[boff]);
            acc = __builtin_amdgcn_mfma_f32_32x32x16_bf16(ah, bh, acc, 0, 0, 0);
            acc = __builtin_amdgcn_mfma_f32_32x32x16_bf16(ah, bl, acc, 0, 0, 0);
            acc = __builtin_amdgcn_mfma_f32_32x32x16_bf16(al, bh, acc, 0, 0, 0);
        }
    }

    if (lhf == 0) {
        int y = y0 + myrow;
        int x0 = xbase + pt * 32 + ln31;
        #pragma unroll
        for (int r = 0; r < 3; ++r) {
            float v = 2.f / (1.f + expf(-acc[r])) - 1.f;
            out[(((size_t)b * 3 + r) * 256 + y) * 256 + x0] = v;
        }
    }
}

// ---------------- codebook prep: bf16 hi/lo frag pack + ce2 + zero counts --
__global__ void prep_codebook(const float* __restrict__ cb,
                              unsigned short* __restrict__ cbh,
                              unsigned short* __restrict__ cbl,
                              float* __restrict__ ce2,
                              unsigned int* __restrict__ counts)
{
    int k = blockIdx.x * 256 + threadIdx.x;
    if (k >= 1024) return;
    float s = 0.f;
    for (int d = 0; d < 128; ++d) {
        float v = cb[k * 128 + d];
        s = fmaf(v, v, s);
        unsigned short h = f2bf(v);
        int kk = d >> 4, t = d & 15;
        cbh[(kk * 1024 + k) * 16 + t] = h;
        cbl[(kk * 1024 + k) * 16 + t] = f2bf(v - bf2f(h));
    }
    ce2[k] = s;
    counts[k] = 0u;
}

// ---------------- VQ part A: MFMA distances + argmin -> gidx ---------------
// 8 waves = 8 code-groups of 128; 6 MFMA per codebook load-pair, dual
// px-tile accumulators; z frags staged in LDS fragment order.
__global__ __launch_bounds__(512) void vq_dist_k(
    const float* __restrict__ z,
    const unsigned short* __restrict__ cbh,
    const unsigned short* __restrict__ cbl,
    const float* __restrict__ ce2,
    unsigned int* __restrict__ counts, int* __restrict__ gidx)
{
    __shared__ unsigned short zfh_l[2][8][64][8];   // [pxg][kk][lane][j] hi
    __shared__ unsigned short zfl_l[2][8][64][8];   // lo
    __shared__ float ce2l[1024];
    __shared__ float cmbd[8][64];
    __shared__ int   cmbi[8][64];

    int tid = threadIdx.x;
    int lane = tid & 63;
    int w = tid >> 6;                  // wave = code group (128 codes)
    int ln31 = lane & 31;
    int lhf = lane >> 5;
    int p0g = blockIdx.x * 64;
    int b = p0g >> 12;
    int p0 = p0g & 4095;

    for (int i = tid; i < 8192; i += 512) {
        int d = i >> 6, px = i & 63;
        float v = z[((size_t)b * 128 + d) * 4096 + p0 + px];
        unsigned short h = f2bf(v);
        int kk = d >> 4;
        int lhf2 = (d >> 3) & 1;
        int j = d & 7;
        int lane2 = lhf2 * 32 + (px & 31);
        int pxg2 = px >> 5;
        zfh_l[pxg2][kk][lane2][j] = h;
        zfl_l[pxg2][kk][lane2][j] = f2bf(v - bf2f(h));
    }
    for (int i = tid; i < 1024; i += 512) ce2l[i] = ce2[i];
    __syncthreads();

    const unsigned short* zh0 = &zfh_l[0][0][lane][0];   // kk stride 512 shorts
    const unsigned short* zl0 = &zfl_l[0][0][lane][0];
    const unsigned short* zh1 = &zfh_l[1][0][lane][0];
    const unsigned short* zl1 = &zfl_l[1][0][lane][0];

    float best0 = 3.4e38f, best1 = 3.4e38f;
    int bidx0 = 0, bidx1 = 0;

    for (int ct = 0; ct < 4; ++ct) {
        int c0 = w * 128 + ct * 32;
        f32x16 acc0 = {};
        f32x16 acc1 = {};
        #pragma unroll
        for (int kk = 0; kk < 8; ++kk) {
            size_t ao = ((size_t)(kk * 1024 + c0 + ln31)) * 16 + lhf * 8;
            short8v ah = *reinterpret_cast<const short8v*>(cbh + ao);
            short8v al = *reinterpret_cast<const short8v*>(cbl + ao);
            short8v bh0 = *reinterpret_cast<const short8v*>(zh0 + kk * 512);
            short8v bl0 = *reinterpret_cast<const short8v*>(zl0 + kk * 512);
            short8v bh1 = *reinterpret_cast<const short8v*>(zh1 + kk * 512);
            short8v bl1 = *reinterpret_cast<const short8v*>(zl1 + kk * 512);
            acc0 = __builtin_amdgcn_mfma_f32_32x32x16_bf16(ah, bh0, acc0, 0, 0, 0);
            acc1 = __builtin_amdgcn_mfma_f32_32x32x16_bf16(ah, bh1, acc1, 0, 0, 0);
            acc0 = __builtin_amdgcn_mfma_f32_32x32x16_bf16(ah, bl0, acc0, 0, 0, 0);
            acc1 = __builtin_amdgcn_mfma_f32_32x32x16_bf16(ah, bl1, acc1, 0, 0, 0);
            acc0 = __builtin_amdgcn_mfma_f32_32x32x16_bf16(al, bh0, acc0, 0, 0, 0);
            acc1 = __builtin_amdgcn_mfma_f32_32x32x16_bf16(al, bh1, acc1, 0, 0, 0);
        }
        #pragma unroll
        for (int r = 0; r < 16; ++r) {
            int code = c0 + (r & 3) + 8 * (r >> 2) + 4 * lhf;
            float ce = ce2l[code];
            float d0 = ce - 2.f * acc0[r];
            float d1 = ce - 2.f * acc1[r];
            if (d0 < best0 || (d0 == best0 && code < bidx0)) { best0 = d0; bidx0 = code; }
            if (d1 < best1 || (d1 == best1 && code < bidx1)) { best1 = d1; bidx1 = code; }
        }
    }

    {
        float ob = __shfl_xor(best0, 32);
        int   oi = __shfl_xor(bidx0, 32);
        if (ob < best0 || (ob == best0 && oi < bidx0)) { best0 = ob; bidx0 = oi; }
        ob = __shfl_xor(best1, 32);
        oi = __shfl_xor(bidx1, 32);
        if (ob < best1 || (ob == best1 && oi < bidx1)) { best1 = ob; bidx1 = oi; }
    }
    if (lane < 32) {
        cmbd[w][ln31] = best0;      cmbi[w][ln31] = bidx0;
        cmbd[w][32 + ln31] = best1; cmbi[w][32 + ln31] = bidx1;
    }
    __syncthreads();
    if (tid < 64) {
        float bv = cmbd[0][tid]; int bi = cmbi[0][tid];
        #pragma unroll
        for (int g = 1; g < 8; ++g) {
            float ov = cmbd[g][tid]; int oi = cmbi[g][tid];
            if (ov < bv || (ov == bv && oi < bi)) { bv = ov; bi = oi; }
        }
        gidx[p0g + tid] = bi;
        atomicAdd(&counts[bi], 1u);
    }
}

// ---------------- VQ part B: gather codebook rows, write q, loss partials --
__global__ __launch_bounds__(512) void vq_gather_k(
    const float* __restrict__ z, const float* __restrict__ cb,
    const int* __restrict__ gidx, float* __restrict__ q,
    double* __restrict__ partial)
{
    __shared__ float red[8];
    int tid = threadIdx.x;
    int lane = tid & 63;
    int w = tid >> 6;
    int p0g = blockIdx.x * 64;
    int b = p0g >> 12;
    int p0 = p0g & 4095;

    int pix = tid & 63, dg = tid >> 6;
    int kidx = gidx[p0g + pix];
    const float* crow = cb + (size_t)kidx * 128 + dg * 16;
    float sq = 0.f;
    size_t zbase = ((size_t)b * 128 + dg * 16) * 4096 + p0 + pix;
    #pragma unroll
    for (int ii = 0; ii < 4; ++ii) {
        float4 c4 = *reinterpret_cast<const float4*>(crow + 4 * ii);
        float vals[4] = {c4.x, c4.y, c4.z, c4.w};
        #pragma unroll
        for (int jj = 0; jj < 4; ++jj) {
            int dl = ii * 4 + jj;
            float qv = vals[jj];
            float zv = z[zbase + (size_t)dl * 4096];
            float df = qv - zv;
            sq = fmaf(df, df, sq);
            q[zbase + (size_t)dl * 4096] = qv;
        }
    }
    #pragma unroll
    for (int off = 32; off > 0; off >>= 1) sq += __shfl_xor(sq, off);
    if (lane == 0) red[w] = sq;
    __syncthreads();
    if (tid == 0) {
        double s = 0.0;
        #pragma unroll
        for (int ww = 0; ww < 8; ++ww) s += (double)red[ww];
        partial[blockIdx.x] = s;
    }
}

// ---------------- finalize ----------------
__global__ __launch_bounds__(256) void finalize_kernel(
    const double* __restrict__ partial, const unsigned int* __restrict__ counts,
    float* __restrict__ dout)
{
    __shared__ double sd[256];
    __shared__ double lossSh;
    int tid = threadIdx.x;
    double s = 0.0;
    for (int i = tid; i < 512; i += 256) s += partial[i];
    sd[tid] = s; __syncthreads();
    for (int off = 128; off > 0; off >>= 1) {
        if (tid < off) sd[tid] += sd[tid + off];
        __syncthreads();
    }
    if (tid == 0) lossSh = CC_COST * sd[0] / 4194304.0;
    __syncthreads();

    double h = 0.0;
    for (int k = tid; k < 1024; k += 256) {
        double pp = (double)counts[k] / 32768.0;
        h += pp * log(pp + 1e-10);
    }
    sd[tid] = h; __syncthreads();
    for (int off = 128; off > 0; off >>= 1) {
        if (tid < off) sd[tid] += sd[tid + off];
        __syncthreads();
    }
    if (tid == 0) {
        dout[0]       = (float)lossSh;
        dout[1572865] = (float)exp(-sd[0]);
    }
}

// ===========================================================================
extern "C" void kernel_launch(void* const* d_in, const int* in_sizes, int n_in,
                              void* d_out, int out_size, void* d_ws, size_t ws_size,
                              hipStream_t stream)
{
    const float* x        = (const float*)d_in[0];
    const float* enc_c1   = (const float*)d_in[1];
    const float* enc_c2   = (const float*)d_in[2];
    const float* enc_c3   = (const float*)d_in[3];
    const float* enc_r1a  = (const float*)d_in[4];
    const float* enc_r1b  = (const float*)d_in[5];
    const float* enc_r2a  = (const float*)d_in[6];
    const float* enc_r2b  = (const float*)d_in[7];
    const float* pre_vq_w = (const float*)d_in[8];
    const float* codebook = (const float*)d_in[9];
    const float* dec_c1   = (const float*)d_in[10];
    const float* dec_r1a  = (const float*)d_in[11];
    const float* dec_r1b  = (const float*)d_in[12];
    const float* dec_r2a  = (const float*)d_in[13];
    const float* dec_r2b  = (const float*)d_in[14];
    const float* dec_dc   = (const float*)d_in[15];
    const float* dec_c3   = (const float*)d_in[16];
    float* dout = (float*)d_out;

    char* wsp = (char*)d_ws;
    auto alloc = [&](size_t bytes) {
        void* p = (void*)wsp;
        wsp += (bytes + 255) & ~(size_t)255;
        return p;
    };
    float* h1   = (float*)alloc(8ull*64*128*128*4);   // 32MB; also qb alias
    float* bufA = (float*)alloc(8ull*128*64*64*4);    // 16MB; also zb alias
    float* bufB = (float*)alloc(8ull*128*64*64*4);    // 16MB
    unsigned short* cbh = (unsigned short*)alloc(131072*2);  // [8][1024][16]
    unsigned short* cbl = (unsigned short*)alloc(131072*2);
    float* ce2  = (float*)alloc(1024*4);
    unsigned int* counts = (unsigned int*)alloc(1024*4);
    double* partial = (double*)alloc(512*8);
    int* gidx = (int*)alloc(32768*4);
    float* wt_ec1  = (float*)alloc(3072*4);
    float* wt_pvq  = (float*)alloc(16384*4);
    unsigned short* w3hi_e = (unsigned short*)alloc(147456*2);
    unsigned short* w3lo_e = (unsigned short*)alloc(147456*2);
    unsigned short* w3hi_d = (unsigned short*)alloc(147456*2);
    unsigned short* w3lo_d = (unsigned short*)alloc(147456*2);
    unsigned short* w4hi   = (unsigned short*)alloc(131072*2);
    unsigned short* w4lo   = (unsigned short*)alloc(131072*2);
    unsigned short* wdchi  = (unsigned short*)alloc(131072*2);
    unsigned short* wdclo  = (unsigned short*)alloc(131072*2);
    unsigned short* wr1aeh = (unsigned short*)alloc(36864*2);
    unsigned short* wr1ael = (unsigned short*)alloc(36864*2);
    unsigned short* wr2aeh = (unsigned short*)alloc(36864*2);
    unsigned short* wr2ael = (unsigned short*)alloc(36864*2);
    unsigned short* wr1adh = (unsigned short*)alloc(36864*2);
    unsigned short* wr1adl = (unsigned short*)alloc(36864*2);
    unsigned short* wr2adh = (unsigned short*)alloc(36864*2);
    unsigned short* wr2adl = (unsigned short*)alloc(36864*2);
    unsigned short* w1e1h  = (unsigned short*)alloc(4096*2);
    unsigned short* w1e1l  = (unsigned short*)alloc(4096*2);
    unsigned short* w1e2h  = (unsigned short*)alloc(4096*2);
    unsigned short* w1e2l  = (unsigned short*)alloc(4096*2);
    unsigned short* w1d1h  = (unsigned short*)alloc(4096*2);
    unsigned short* w1d1l  = (unsigned short*)alloc(4096*2);
    unsigned short* w1d2h  = (unsigned short*)alloc(4096*2);
    unsigned short* w1d2l  = (unsigned short*)alloc(4096*2);
    unsigned short* wuph   = (unsigned short*)alloc(18432*2);
    unsigned short* wupl   = (unsigned short*)alloc(18432*2);
    float* zb = bufA;   // alias: pre_vq out (reads bufB), dead before dec writes bufA
    float* qb = h1;     // alias: dead before deconv overwrites h1

    // VQ prep: bf16 frag pack + ce2 + zero counts
    prep_codebook<<<4, 256, 0, stream>>>(codebook, cbh, cbl, ce2, counts);

    // batched weight transforms (2 fp32 jobs; MFMA layers use split kernels)
    WtJobs J;
    const float* srcs[2] = {enc_c1, pre_vq_w};
    float* dsts[2] = {wt_ec1, wt_pvq};
    int couts[2] = {64, 128};
    int cins[2]  = {3, 128};
    int kks[2]   = {16, 1};
    int kinds[2] = {0, 0};
    int off = 0;
    for (int j = 0; j < 2; ++j) {
        J.src[j] = srcs[j]; J.dst[j] = dsts[j];
        J.cout[j] = couts[j]; J.cin[j] = cins[j]; J.kk[j] = kks[j];
        J.kind[j] = kinds[j];
        J.blk0[j] = off;
        off += (couts[j] * cins[j] * kks[j] + 255) / 256;
    }
    J.blk0[2] = off;
    for (int j = 3; j < 16; ++j) J.blk0[j] = off + 1000000;  // sentinels
    wt_batch_k<<<off, 256, 0, stream>>>(J);
    wt_split_k<<<576, 256, 0, stream>>>(enc_c3, w3hi_e, w3lo_e);
    wt_split_k<<<576, 256, 0, stream>>>(dec_c1, w3hi_d, w3lo_d);
    wt_split4_k<<<512, 256, 0, stream>>>(enc_c2, w4hi, w4lo);
    wt_split_dc_k<<<512, 256, 0, stream>>>(dec_dc, wdchi, wdclo);
    wt_split_r_k<<<144, 256, 0, stream>>>(enc_r1a, wr1aeh, wr1ael);
    wt_split_r_k<<<144, 256, 0, stream>>>(enc_r2a, wr2aeh, wr2ael);
    wt_split_r_k<<<144, 256, 0, stream>>>(dec_r1a, wr1adh, wr1adl);
    wt_split_r_k<<<144, 256, 0, stream>>>(dec_r2a, wr2adh, wr2adl);
    wt_split_1x1_k<<<16, 256, 0, stream>>>(enc_r1b, w1e1h, w1e1l);
    wt_split_1x1_k<<<16, 256, 0, stream>>>(enc_r2b, w1e2h, w1e2l);
    wt_split_1x1_k<<<16, 256, 0, stream>>>(dec_r1b, w1d1h, w1d1l);
    wt_split_1x1_k<<<16, 256, 0, stream>>>(dec_r2b, w1d2h, w1d2l);
    wt_split_up_k<<<72, 256, 0, stream>>>(dec_c3, wuph, wupl);

    // ---- encoder ----
    conv4x4s2_k<3, 64, 128, 3, 4, 64, 1><<<1024, 256, 0, stream>>>(x, wt_ec1, h1);
    conv4x4s2_mfma<<<256, 512, 0, stream>>>(h1, w4hi, w4lo, bufA);
    conv3x3_mfma<<<256, 512, 0, stream>>>(bufA, w3hi_e, w3lo_e, bufB);
    fused_res_k<<<512, 512, 0, stream>>>(bufB, wr1aeh, wr1ael, w1e1h, w1e1l, bufA);
    fused_res_k<<<512, 512, 0, stream>>>(bufA, wr2aeh, wr2ael, w1e2h, w1e2l, bufB);
    conv1x1_k<128, 128, 32, true, false><<<512, 256, 0, stream>>>(bufB, wt_pvq, bufB, zb);

    // ---- VQ (split: distances+argmin, then gather/q/loss) ----
    vq_dist_k<<<512, 512, 0, stream>>>(zb, cbh, cbl, ce2, counts, gidx);
    vq_gather_k<<<512, 512, 0, stream>>>(zb, codebook, gidx, qb, partial);

    // ---- decoder ----
    conv3x3_mfma<<<256, 512, 0, stream>>>(qb, w3hi_d, w3lo_d, bufA);
    fused_res_k<<<512, 512, 0, stream>>>(bufA, wr1adh, wr1adl, w1d1h, w1d1l, bufB);
    fused_res_k<<<512, 512, 0, stream>>>(bufB, wr2adh, wr2adl, w1d2h, w1d2l, bufA);
    deconv_mfma<<<512, 512, 0, stream>>>(bufA, wdchi, wdclo, h1);
    upconv_mfma<<<2048, 512, 0, stream>>>(h1, wuph, wupl, dout + 1);

    // ---- scalars ----
    finalize_kernel<<<1, 256, 0, stream>>>(partial, counts, dout);
}

// Round 26
// 646.079 us; speedup vs baseline: 1.1278x; 1.1278x over previous
//
#include <hip/hip_runtime.h>
#include <hip/hip_bf16.h>
#include <math.h>

#define CC_COST 0.25

typedef __attribute__((ext_vector_type(8))) short short8v;
typedef __attribute__((ext_vector_type(4))) float f32x4;
typedef __attribute__((ext_vector_type(16))) float f32x16;

__device__ __forceinline__ unsigned short f2bf(float f) {
    unsigned u = __float_as_uint(f);
    unsigned r = (u + 0x7FFFu + ((u >> 16) & 1u)) >> 16;
    return (unsigned short)r;
}
__device__ __forceinline__ float bf2f(unsigned short h) {
    return __uint_as_float(((unsigned)h) << 16);
}

// ===========================================================================
// VQ-VAE forward. All heavy convs + VQ GEMM on MFMA (bf16 hi/lo 3-product).
// Res blocks fully fused; upconv on MFMA; VQ split into dist+argmin (no
// contended atomics), LDS-privatized histogram, and streaming gather/loss.
// d_out[0]=loss, [1..]=recon, [last]=perplexity
// ===========================================================================

// ---------------- batched weight transforms (fp32 vector kernels) ----------
struct WtJobs {
    const float* src[15];
    float* dst[15];
    int cout[15], cin[15], kk[15], kind[15];
    int blk0[16];
};

__global__ void wt_batch_k(WtJobs J)
{
    int blk = blockIdx.x;
    int j = 0;
    while (j < 14 && blk >= J.blk0[j + 1]) ++j;
    int i = (blk - J.blk0[j]) * 256 + threadIdx.x;
    int total = J.cout[j] * J.cin[j] * J.kk[j];
    if (i >= total) return;
    const float* src = J.src[j];
    float* dst = J.dst[j];
    int kind = J.kind[j];
    if (kind == 0) {
        int Cout = J.cout[j], Cin = J.cin[j], KK = J.kk[j];
        int oc = i % Cout; int t2 = i / Cout; int t = t2 % KK; int c = t2 / KK;
        dst[i] = src[(oc * Cin + c) * KK + t];
    } else {
        int o = i % 3; int t = (i / 3) % 9; int c = i / 27;
        dst[i] = src[(o * 64 + c) * 9 + t];
    }
}

// split OIHW [128][128][3][3] fp32 -> whi/wlo bf16 in [9 tap][8 cb][128 oc][16 ci]
__global__ void wt_split_k(const float* __restrict__ w,
                           unsigned short* __restrict__ whi,
                           unsigned short* __restrict__ wlo)
{
    int i = blockIdx.x * 256 + threadIdx.x;
    if (i >= 147456) return;
    int ci = i & 15;
    int oc = (i >> 4) & 127;
    int rest = i >> 11;           // 0..71
    int cb = rest & 7;
    int tap = rest >> 3;          // 0..8
    float v = w[(oc * 128 + cb * 16 + ci) * 9 + tap];
    unsigned short h = f2bf(v);
    whi[i] = h;
    wlo[i] = f2bf(v - bf2f(h));
}

// split enc_c2 OIHW [128][64][4][4] -> [16 tap][4 cb][128 oc][16 ci] hi/lo
__global__ void wt_split4_k(const float* __restrict__ w,
                            unsigned short* __restrict__ whi,
                            unsigned short* __restrict__ wlo)
{
    int i = blockIdx.x * 256 + threadIdx.x;
    if (i >= 131072) return;
    int t = i & 15;
    int oc = (i >> 4) & 127;
    int rest = i >> 11;           // 0..63
    int cb = rest & 3;
    int tap = rest >> 2;          // 0..15
    float v = w[(oc * 64 + cb * 16 + t) * 16 + tap];
    unsigned short h = f2bf(v);
    whi[i] = h;
    wlo[i] = f2bf(v - bf2f(h));
}

// split dec_dc [128 cin][64 oc][4 ky][4 kx] -> [ky4][kx4][cb8][64 oc][16 ci] hi/lo
__global__ void wt_split_dc_k(const float* __restrict__ w,
                              unsigned short* __restrict__ whi,
                              unsigned short* __restrict__ wlo)
{
    int i = blockIdx.x * 256 + threadIdx.x;
    if (i >= 131072) return;
    int ci = i & 15;
    int oc = (i >> 4) & 63;
    int cb = (i >> 10) & 7;
    int kx = (i >> 13) & 3;
    int ky = i >> 15;
    float v = w[((size_t)(cb * 16 + ci) * 64 + oc) * 16 + ky * 4 + kx];
    unsigned short h = f2bf(v);
    whi[i] = h;
    wlo[i] = f2bf(v - bf2f(h));
}

// split res conv3x3 OIHW [32][128][3][3] -> [9 tap][4 cb][32 oc][32 k] hi/lo
__global__ void wt_split_r_k(const float* __restrict__ w,
                             unsigned short* __restrict__ whi,
                             unsigned short* __restrict__ wlo)
{
    int i = blockIdx.x * 256 + threadIdx.x;
    if (i >= 36864) return;
    int k5 = i & 31;
    int oc = (i >> 5) & 31;
    int cb = (i >> 10) & 3;
    int tap = i >> 12;            // 0..8
    float v = w[(oc * 128 + cb * 32 + k5) * 9 + tap];
    unsigned short h = f2bf(v);
    whi[i] = h;
    wlo[i] = f2bf(v - bf2f(h));
}

// split res conv1x1 [128 out][32 in] -> [2 kk][128 oc][16 ci] hi/lo
__global__ void wt_split_1x1_k(const float* __restrict__ w,
                               unsigned short* __restrict__ whi,
                               unsigned short* __restrict__ wlo)
{
    int i = blockIdx.x * 256 + threadIdx.x;
    if (i >= 4096) return;
    int ci = i & 15;
    int oc = (i >> 4) & 127;
    int kk = i >> 11;
    float v = w[oc * 32 + kk * 16 + ci];
    unsigned short h = f2bf(v);
    whi[i] = h;
    wlo[i] = f2bf(v - bf2f(h));
}

// split dec_c3 [3][64][3][3] -> [9 tap][4 cb][32 oc(3 used)][16 ci] hi/lo
__global__ void wt_split_up_k(const float* __restrict__ w,
                              unsigned short* __restrict__ whi,
                              unsigned short* __restrict__ wlo)
{
    int i = blockIdx.x * 256 + threadIdx.x;
    if (i >= 18432) return;
    int ci = i & 15;
    int oc = (i >> 4) & 31;
    int cb = (i >> 9) & 3;
    int tap = i >> 11;            // 0..8
    float v = 0.f;
    if (oc < 3) {
        int ch = cb * 16 + ci;
        v = w[(oc * 64 + ch) * 9 + tap];
    }
    unsigned short h = f2bf(v);
    whi[i] = h;
    wlo[i] = f2bf(v - bf2f(h));
}

// ---------------- MFMA conv3x3 s1 p1, 128->128, 64x64, batch 8 -------------
__global__ __launch_bounds__(512) void conv3x3_mfma(
    const float* __restrict__ in,           // [8,128,64,64]
    const unsigned short* __restrict__ whi, // [9][8][128][16] bf16
    const unsigned short* __restrict__ wlo,
    float* __restrict__ out)                // [8,128,64,64]
{
    constexpr int CST = 40;
    __shared__ unsigned short ls_hi[4 * 68 * CST];
    __shared__ unsigned short ls_lo[4 * 68 * CST];

    int tid = threadIdx.x;
    int lane = tid & 63;
    int w = tid >> 6;
    int myrow = w & 1;
    int oc0 = (w >> 1) * 32;
    int y0 = (blockIdx.x & 31) * 2;
    int b  = blockIdx.x >> 5;
    int ln31 = lane & 31;
    int lhf  = lane >> 5;

    f32x16 acc0 = {};
    f32x16 acc1 = {};

    const float* inb = in + (size_t)b * 128 * 4096;

    for (int chunk = 0; chunk < 4; ++chunk) {
        int c0 = chunk * 32;
        __syncthreads();
        for (int i = tid; i < 4 * 66 * 16; i += 512) {
            int x = i % 66;
            int t = i / 66;
            int cp = t & 15;
            int r = t >> 4;
            int gy = y0 - 1 + r, gx = x - 1;
            float v0 = 0.f, v1 = 0.f;
            if ((unsigned)gy < 64u && (unsigned)gx < 64u) {
                const float* p = inb + (size_t)(c0 + 2 * cp) * 4096 + gy * 64 + gx;
                v0 = p[0];
                v1 = p[4096];
            }
            unsigned short h0 = f2bf(v0), h1 = f2bf(v1);
            unsigned short l0 = f2bf(v0 - bf2f(h0)), l1 = f2bf(v1 - bf2f(h1));
            int a = (r * 68 + x) * CST + 2 * cp;
            *reinterpret_cast<unsigned int*>(&ls_hi[a]) = (unsigned)h0 | ((unsigned)h1 << 16);
            *reinterpret_cast<unsigned int*>(&ls_lo[a]) = (unsigned)l0 | ((unsigned)l1 << 16);
        }
        __syncthreads();

        #pragma unroll
        for (int tap = 0; tap < 9; ++tap) {
            int dy = tap / 3, dx = tap - 3 * (tap / 3);
            int rbase = (myrow + dy) * 68;
            #pragma unroll
            for (int cb = 0; cb < 2; ++cb) {
                int cbg = chunk * 2 + cb;
                size_t wofs = (((size_t)tap * 8 + cbg) * 128 + oc0 + ln31) * 16 + lhf * 8;
                short8v ah = *reinterpret_cast<const short8v*>(whi + wofs);
                short8v al = *reinterpret_cast<const short8v*>(wlo + wofs);
                int k0 = cb * 16 + lhf * 8;
                int xo0 = (rbase + ln31 + dx) * CST + k0;
                int xo1 = (rbase + 32 + ln31 + dx) * CST + k0;
                short8v bh0 = *reinterpret_cast<const short8v*>(&ls_hi[xo0]);
                short8v bl0 = *reinterpret_cast<const short8v*>(&ls_lo[xo0]);
                short8v bh1 = *reinterpret_cast<const short8v*>(&ls_hi[xo1]);
                short8v bl1 = *reinterpret_cast<const short8v*>(&ls_lo[xo1]);
                acc0 = __builtin_amdgcn_mfma_f32_32x32x16_bf16(ah, bh0, acc0, 0, 0, 0);
                acc1 = __builtin_amdgcn_mfma_f32_32x32x16_bf16(ah, bh1, acc1, 0, 0, 0);
                acc0 = __builtin_amdgcn_mfma_f32_32x32x16_bf16(ah, bl0, acc0, 0, 0, 0);
                acc1 = __builtin_amdgcn_mfma_f32_32x32x16_bf16(ah, bl1, acc1, 0, 0, 0);
                acc0 = __builtin_amdgcn_mfma_f32_32x32x16_bf16(al, bh0, acc0, 0, 0, 0);
                acc1 = __builtin_amdgcn_mfma_f32_32x32x16_bf16(al, bh1, acc1, 0, 0, 0);
            }
        }
    }

    float* ob = out + (size_t)b * 128 * 4096 + (size_t)(y0 + myrow) * 64;
    #pragma unroll
    for (int r = 0; r < 16; ++r) {
        int oc = oc0 + (r & 3) + 8 * (r >> 2) + 4 * lhf;
        ob[(size_t)oc * 4096 + ln31]      = acc0[r];
        ob[(size_t)oc * 4096 + 32 + ln31] = acc1[r];
    }
}

// ---------------- MFMA conv4x4 s2 p1, 64->128, in 128x128 -> out 64x64 -----
__global__ __launch_bounds__(512) void conv4x4s2_mfma(
    const float* __restrict__ in,            // [8,64,128,128] post-relu
    const unsigned short* __restrict__ whi,  // [16 tap][4 cb][128 oc][16 ci]
    const unsigned short* __restrict__ wlo,
    float* __restrict__ out)                 // [8,128,64,64], relu out
{
    constexpr int CST = 24;                  // 16 ci + 8 pad (48B = 16B-aligned)
    __shared__ unsigned short lsEh[6 * 65 * CST];
    __shared__ unsigned short lsEl[6 * 65 * CST];
    __shared__ unsigned short lsOh[6 * 65 * CST];
    __shared__ unsigned short lsOl[6 * 65 * CST];

    int tid = threadIdx.x;
    int lane = tid & 63;
    int w = tid >> 6;
    int myrow = w & 1;
    int oc0 = (w >> 1) * 32;
    int y0 = (blockIdx.x & 31) * 2;
    int b  = blockIdx.x >> 5;
    int ln31 = lane & 31;
    int lhf  = lane >> 5;

    f32x16 acc0 = {};
    f32x16 acc1 = {};

    const float* inb = in + (size_t)b * 64 * 16384;

    for (int cb = 0; cb < 4; ++cb) {
        int c0 = cb * 16;
        __syncthreads();
        for (int i = tid; i < 12480; i += 512) {
            int gxi = i % 130; int t2 = i / 130;
            int r = t2 % 6; int cc = t2 / 6;
            int gx = gxi - 1;
            int gy = 2 * y0 - 1 + r;
            float v = 0.f;
            if ((unsigned)gy < 128u && (unsigned)gx < 128u)
                v = inb[(size_t)(c0 + cc) * 16384 + gy * 128 + gx];
            unsigned short h = f2bf(v);
            unsigned short l = f2bf(v - bf2f(h));
            if (gx & 1) {
                int a = (r * 65 + ((gx + 1) >> 1)) * CST + cc;
                lsOh[a] = h; lsOl[a] = l;
            } else {
                int a = (r * 65 + (gx >> 1)) * CST + cc;
                lsEh[a] = h; lsEl[a] = l;
            }
        }
        __syncthreads();

        #pragma unroll
        for (int tap = 0; tap < 16; ++tap) {
            int ky = tap >> 2, kx = tap & 3;
            int ridx = 2 * myrow + ky;
            int dlt = kx >> 1;
            const unsigned short* ph = (kx & 1) ? lsEh : lsOh;
            const unsigned short* pl = (kx & 1) ? lsEl : lsOl;
            size_t aoff = ((size_t)((tap * 4 + cb) * 128 + oc0 + ln31)) * 16 + lhf * 8;
            short8v ah = *reinterpret_cast<const short8v*>(whi + aoff);
            short8v al = *reinterpret_cast<const short8v*>(wlo + aoff);
            int base0 = (ridx * 65 + ln31 + dlt) * CST + lhf * 8;
            int base1 = (ridx * 65 + 32 + ln31 + dlt) * CST + lhf * 8;
            short8v bh0 = *reinterpret_cast<const short8v*>(ph + base0);
            short8v bl0 = *reinterpret_cast<const short8v*>(pl + base0);
            short8v bh1 = *reinterpret_cast<const short8v*>(ph + base1);
            short8v bl1 = *reinterpret_cast<const short8v*>(pl + base1);
            acc0 = __builtin_amdgcn_mfma_f32_32x32x16_bf16(ah, bh0, acc0, 0, 0, 0);
            acc1 = __builtin_amdgcn_mfma_f32_32x32x16_bf16(ah, bh1, acc1, 0, 0, 0);
            acc0 = __builtin_amdgcn_mfma_f32_32x32x16_bf16(ah, bl0, acc0, 0, 0, 0);
            acc1 = __builtin_amdgcn_mfma_f32_32x32x16_bf16(ah, bl1, acc1, 0, 0, 0);
            acc0 = __builtin_amdgcn_mfma_f32_32x32x16_bf16(al, bh0, acc0, 0, 0, 0);
            acc1 = __builtin_amdgcn_mfma_f32_32x32x16_bf16(al, bh1, acc1, 0, 0, 0);
        }
    }

    int y = y0 + myrow;
    float* ob = out + (size_t)b * 128 * 4096 + (size_t)y * 64;
    #pragma unroll
    for (int r = 0; r < 16; ++r) {
        int oc = oc0 + (r & 3) + 8 * (r >> 2) + 4 * lhf;
        ob[(size_t)oc * 4096 + ln31]      = fmaxf(acc0[r], 0.f);
        ob[(size_t)oc * 4096 + 32 + ln31] = fmaxf(acc1[r], 0.f);
    }
}

// ---------------- MFMA deconv 4x4 s2 p1, 128->64, relu(in), relu(out) ------
__global__ __launch_bounds__(512) void deconv_mfma(
    const float* __restrict__ in,            // [8,128,64,64] pre-relu
    const unsigned short* __restrict__ whi,  // [ky4][kx4][cb8][64 oc][16 ci]
    const unsigned short* __restrict__ wlo,
    float* __restrict__ out)                 // [8,64,128,128] relu
{
    constexpr int CST = 40;
    __shared__ unsigned short ls_hi[3 * 68 * CST];
    __shared__ unsigned short ls_lo[3 * 68 * CST];

    int tid = threadIdx.x;
    int lane = tid & 63;
    int w = tid >> 6;
    int myrow = w & 1;                 // output row oy = 2*yb + myrow
    int oc0 = ((w >> 1) & 1) * 32;     // oc tile
    int oxp = w >> 2;                  // ox parity (0 even, 1 odd)
    int yb = blockIdx.x & 63;
    int b  = blockIdx.x >> 6;
    int ln31 = lane & 31;
    int lhf  = lane >> 5;

    f32x16 acc0 = {};
    f32x16 acc1 = {};

    const float* inb = in + (size_t)b * 128 * 4096;

    for (int chunk = 0; chunk < 4; ++chunk) {
        int c0 = chunk * 32;
        __syncthreads();
        for (int i = tid; i < 3 * 66 * 16; i += 512) {
            int x = i % 66;
            int t = i / 66;
            int cp = t & 15;
            int r = t >> 4;            // 0..2
            int gy = yb - 1 + r, gx = x - 1;
            float v0 = 0.f, v1 = 0.f;
            if ((unsigned)gy < 64u && (unsigned)gx < 64u) {
                const float* p = inb + (size_t)(c0 + 2 * cp) * 4096 + gy * 64 + gx;
                v0 = fmaxf(p[0], 0.f);
                v1 = fmaxf(p[4096], 0.f);
            }
            unsigned short h0 = f2bf(v0), h1 = f2bf(v1);
            unsigned short l0 = f2bf(v0 - bf2f(h0)), l1 = f2bf(v1 - bf2f(h1));
            int a = (r * 68 + x) * CST + 2 * cp;
            *reinterpret_cast<unsigned int*>(&ls_hi[a]) = (unsigned)h0 | ((unsigned)h1 << 16);
            *reinterpret_cast<unsigned int*>(&ls_lo[a]) = (unsigned)l0 | ((unsigned)l1 << 16);
        }
        __syncthreads();

        #pragma unroll
        for (int tki = 0; tki < 2; ++tki) {
            int ky = (1 - myrow) + 2 * tki;
            int ldsrow = 1 + myrow - tki;
            #pragma unroll
            for (int txi = 0; txi < 2; ++txi) {
                int kx = (1 - oxp) + 2 * txi;
                int dlt = oxp - txi;           // ix = dlt + lane index
                #pragma unroll
                for (int cb = 0; cb < 2; ++cb) {
                    int cbg = chunk * 2 + cb;
                    size_t aoff = ((size_t)(((ky * 4 + kx) * 8 + cbg) * 64 + oc0 + ln31)) * 16 + lhf * 8;
                    short8v ah = *reinterpret_cast<const short8v*>(whi + aoff);
                    short8v al = *reinterpret_cast<const short8v*>(wlo + aoff);
                    int k0 = cb * 16 + lhf * 8;
                    int xo0 = (ldsrow * 68 + ln31 + dlt + 1) * CST + k0;
                    int xo1 = (ldsrow * 68 + 32 + ln31 + dlt + 1) * CST + k0;
                    short8v bh0 = *reinterpret_cast<const short8v*>(&ls_hi[xo0]);
                    short8v bl0 = *reinterpret_cast<const short8v*>(&ls_lo[xo0]);
                    short8v bh1 = *reinterpret_cast<const short8v*>(&ls_hi[xo1]);
                    short8v bl1 = *reinterpret_cast<const short8v*>(&ls_lo[xo1]);
                    acc0 = __builtin_amdgcn_mfma_f32_32x32x16_bf16(ah, bh0, acc0, 0, 0, 0);
                    acc1 = __builtin_amdgcn_mfma_f32_32x32x16_bf16(ah, bh1, acc1, 0, 0, 0);
                    acc0 = __builtin_amdgcn_mfma_f32_32x32x16_bf16(ah, bl0, acc0, 0, 0, 0);
                    acc1 = __builtin_amdgcn_mfma_f32_32x32x16_bf16(ah, bl1, acc1, 0, 0, 0);
                    acc0 = __builtin_amdgcn_mfma_f32_32x32x16_bf16(al, bh0, acc0, 0, 0, 0);
                    acc1 = __builtin_amdgcn_mfma_f32_32x32x16_bf16(al, bh1, acc1, 0, 0, 0);
                }
            }
        }
    }

    int oy = 2 * yb + myrow;
    float* ob = out + (size_t)b * 64 * 16384 + (size_t)oy * 128;
    #pragma unroll
    for (int r = 0; r < 16; ++r) {
        int oc = oc0 + (r & 3) + 8 * (r >> 2) + 4 * lhf;
        ob[(size_t)oc * 16384 + oxp + 2 * ln31]      = fmaxf(acc0[r], 0.f);
        ob[(size_t)oc * 16384 + oxp + 64 + 2 * ln31] = fmaxf(acc1[r], 0.f);
    }
}

// ---------------- fused res block: conv3x3 128->32 + relu + 1x1 32->128 + res
__global__ __launch_bounds__(512) void fused_res_k(
    const float* __restrict__ in,            // [8,128,64,64] pre-relu (+res)
    const unsigned short* __restrict__ whi,  // 3x3 [9][4][32 oc][32 k]
    const unsigned short* __restrict__ wlo,
    const unsigned short* __restrict__ w1hi, // 1x1 [2 kk][128 oc][16 ci]
    const unsigned short* __restrict__ w1lo,
    float* __restrict__ out)                 // [8,128,64,64]
{
    constexpr int CST = 40;
    __shared__ unsigned short ls_hi[3 * 68 * CST];
    __shared__ unsigned short ls_lo[3 * 68 * CST];

    int tid = threadIdx.x;
    int lane = tid & 63;
    int w = tid >> 6;
    int oc0 = (w & 1) * 16;
    int px0 = (w >> 1) * 16;
    int y = blockIdx.x & 63;
    int b = blockIdx.x >> 6;
    int n16 = lane & 15;
    int kk4 = lane >> 4;
    int ln31 = lane & 31;
    int lhf = lane >> 5;

    f32x4 acc = {};
    const float* inb = in + (size_t)b * 128 * 4096;

    for (int cb = 0; cb < 4; ++cb) {
        int c0 = cb * 32;
        __syncthreads();
        for (int i = tid; i < 3 * 66 * 16; i += 512) {
            int x = i % 66;
            int t = i / 66;
            int cp = t & 15;
            int r = t >> 4;            // 0..2
            int gy = y - 1 + r, gx = x - 1;
            float v0 = 0.f, v1 = 0.f;
            if ((unsigned)gy < 64u && (unsigned)gx < 64u) {
                const float* p = inb + (size_t)(c0 + 2 * cp) * 4096 + gy * 64 + gx;
                v0 = fmaxf(p[0], 0.f);
                v1 = fmaxf(p[4096], 0.f);
            }
            unsigned short h0 = f2bf(v0), h1 = f2bf(v1);
            unsigned short l0 = f2bf(v0 - bf2f(h0)), l1 = f2bf(v1 - bf2f(h1));
            int a = (r * 68 + x) * CST + 2 * cp;
            *reinterpret_cast<unsigned int*>(&ls_hi[a]) = (unsigned)h0 | ((unsigned)h1 << 16);
            *reinterpret_cast<unsigned int*>(&ls_lo[a]) = (unsigned)l0 | ((unsigned)l1 << 16);
        }
        __syncthreads();

        #pragma unroll
        for (int tap = 0; tap < 9; ++tap) {
            int dy = tap / 3, dx = tap - 3 * (tap / 3);
            size_t aoff = ((size_t)((tap * 4 + cb) * 32 + oc0 + n16)) * 32 + kk4 * 8;
            short8v ah = *reinterpret_cast<const short8v*>(whi + aoff);
            short8v al = *reinterpret_cast<const short8v*>(wlo + aoff);
            int xo = (dy * 68 + px0 + n16 + dx) * CST + kk4 * 8;
            short8v bh = *reinterpret_cast<const short8v*>(&ls_hi[xo]);
            short8v bl = *reinterpret_cast<const short8v*>(&ls_lo[xo]);
            acc = __builtin_amdgcn_mfma_f32_16x16x32_bf16(ah, bh, acc, 0, 0, 0);
            acc = __builtin_amdgcn_mfma_f32_16x16x32_bf16(ah, bl, acc, 0, 0, 0);
            acc = __builtin_amdgcn_mfma_f32_16x16x32_bf16(al, bh, acc, 0, 0, 0);
        }
    }

    // phase B: relu(P) -> LDS [px][ch] hi/lo (overlay on staging buffers)
    __syncthreads();
    #pragma unroll
    for (int r = 0; r < 4; ++r) {
        int ch = oc0 + kk4 * 4 + r;        // C layout: row=(lane>>4)*4+r
        int px = px0 + n16;                // col = lane&15
        float v = fmaxf(acc[r], 0.f);
        unsigned short h = f2bf(v);
        ls_hi[px * CST + ch] = h;
        ls_lo[px * CST + ch] = f2bf(v - bf2f(h));
    }
    __syncthreads();

    // phase C: 1x1 GEMM 32->128 (2 kk x 3 MFMA 32x32x16)
    int oc1 = (w & 3) * 32;
    int pxt = (w >> 2) * 32;
    f32x16 acc2 = {};
    #pragma unroll
    for (int kk = 0; kk < 2; ++kk) {
        size_t aoff = ((size_t)(kk * 128 + oc1 + ln31)) * 16 + lhf * 8;
        short8v ah = *reinterpret_cast<const short8v*>(w1hi + aoff);
        short8v al = *reinterpret_cast<const short8v*>(w1lo + aoff);
        int boff = (pxt + ln31) * CST + kk * 16 + lhf * 8;
        short8v bh = *reinterpret_cast<const short8v*>(&ls_hi[boff]);
        short8v bl = *reinterpret_cast<const short8v*>(&ls_lo[boff]);
        acc2 = __builtin_amdgcn_mfma_f32_32x32x16_bf16(ah, bh, acc2, 0, 0, 0);
        acc2 = __builtin_amdgcn_mfma_f32_32x32x16_bf16(ah, bl, acc2, 0, 0, 0);
        acc2 = __builtin_amdgcn_mfma_f32_32x32x16_bf16(al, bh, acc2, 0, 0, 0);
    }

    // phase D: residual add (fp32) + store
    float* ob = out + (size_t)b * 128 * 4096 + (size_t)y * 64;
    const float* rb = inb + (size_t)y * 64;
    #pragma unroll
    for (int r = 0; r < 16; ++r) {
        int oc = oc1 + (r & 3) + 8 * (r >> 2) + 4 * lhf;
        size_t o = (size_t)oc * 4096 + pxt + ln31;
        ob[o] = rb[o] + acc2[r];
    }
}

// ---------------- conv 1x1 on 64x64 (COUT must be 128) ----------------
template<int CIN, int COUT, int CC, bool IN_RELU, bool ADD_RES>
__global__ __launch_bounds__(256) void conv1x1_k(
    const float* __restrict__ in, const float* __restrict__ wT,
    const float* __restrict__ res, float* __restrict__ out)
{
    static_assert(COUT == 128, "tile assumes 128");
    __shared__ __align__(16) float ls_in[CC][64];
    __shared__ __align__(16) float ls_w[CC][COUT];
    int tid = threadIdx.x;
    int pxg = tid & 7, ocg = tid >> 3;
    int x0 = pxg * 8, oc0 = ocg * 4;
    int y = blockIdx.x & 63, b = blockIdx.x >> 6;

    float acc[4][8];
    #pragma unroll
    for (int o = 0; o < 4; ++o)
        #pragma unroll
        for (int p = 0; p < 8; ++p) acc[o][p] = 0.f;

    for (int c0 = 0; c0 < CIN; c0 += CC) {
        __syncthreads();
        for (int i = tid; i < CC * 64; i += 256) {
            int xx = i & 63, cc = i >> 6;
            float v = in[(((size_t)b * CIN + c0 + cc) * 64 + y) * 64 + xx];
            if (IN_RELU) v = fmaxf(v, 0.f);
            ls_in[cc][xx] = v;
        }
        const float* wsrc = wT + (size_t)c0 * COUT;
        for (int i = tid; i < CC * COUT; i += 256)
            (&ls_w[0][0])[i] = wsrc[i];
        __syncthreads();

        for (int cc = 0; cc < CC; ++cc) {
            float rv[8];
            const float* base = &ls_in[cc][x0];
            float4 v0 = *reinterpret_cast<const float4*>(base);
            float4 v1 = *reinterpret_cast<const float4*>(base + 4);
            rv[0]=v0.x; rv[1]=v0.y; rv[2]=v0.z; rv[3]=v0.w;
            rv[4]=v1.x; rv[5]=v1.y; rv[6]=v1.z; rv[7]=v1.w;
            float4 w4 = *reinterpret_cast<const float4*>(&ls_w[cc][oc0]);
            float wv[4] = {w4.x, w4.y, w4.z, w4.w};
            #pragma unroll
            for (int p = 0; p < 8; ++p)
                #pragma unroll
                for (int o = 0; o < 4; ++o)
                    acc[o][p] = fmaf(rv[p], wv[o], acc[o][p]);
        }
    }
    #pragma unroll
    for (int o = 0; o < 4; ++o) {
        float* op = out + (((size_t)b * COUT + oc0 + o) * 64 + y) * 64 + x0;
        const float* rp = res + (((size_t)b * COUT + oc0 + o) * 64 + y) * 64 + x0;
        #pragma unroll
        for (int q = 0; q < 2; ++q) {
            float4 v = make_float4(acc[o][4*q], acc[o][4*q+1],
                                   acc[o][4*q+2], acc[o][4*q+3]);
            if (ADD_RES) {
                float4 r4 = *reinterpret_cast<const float4*>(rp + 4 * q);
                v.x += r4.x; v.y += r4.y; v.z += r4.z; v.w += r4.w;
            }
            *reinterpret_cast<float4*>(op + 4 * q) = v;
        }
    }
}

// ---------------- conv 4x4 s2 p1 (vector; used for enc_c1 3->64) -----------
template<int CIN, int COUT, int WOUT, int CC, int OCB, int WOC, int NSLICE>
__global__ __launch_bounds__(256) void conv4x4s2_k(
    const float* __restrict__ in, const float* __restrict__ wT,
    float* __restrict__ out)
{
    constexpr int WIN = WOUT * 2;
    constexpr int NPXG = WOUT / 8, NOCG = COUT / OCB;
    static_assert(NPXG * NOCG == 256, "bad tile");
    constexpr int WUSE = 2 * WOUT + 2;
    constexpr int PADLEN = ((WUSE + (WUSE / 16 + 1) * 4) + 3) & ~3;
    __shared__ __align__(16) float ls_in[CC][4][PADLEN];
    __shared__ __align__(16) float ls_w[CC][16][COUT];

    int tid = threadIdx.x;
    int pxg = tid % NPXG, ocg = tid / NPXG;
    int x0 = pxg * 8, oc0 = ocg * OCB;
    int blk = blockIdx.x;
    int y = blk % WOUT; int rest = blk / WOUT;
    int slice = rest % NSLICE; int b = rest / NSLICE;
    int oc_base = slice * COUT;
    const float* inb = in + (size_t)b * CIN * WIN * WIN;

    float acc[OCB][8];
    #pragma unroll
    for (int o = 0; o < OCB; ++o)
        #pragma unroll
        for (int p = 0; p < 8; ++p) acc[o][p] = 0.f;

    for (int c0 = 0; c0 < CIN; c0 += CC) {
        __syncthreads();
        for (int i = tid; i < CC * 4 * WUSE; i += 256) {
            int xx = i % WUSE; int t = i / WUSE; int r = t & 3; int cc = t >> 2;
            int gy = 2 * y - 1 + r, gx = xx - 1;
            float v = 0.f;
            if ((unsigned)gy < (unsigned)WIN && (unsigned)gx < (unsigned)WIN)
                v = inb[(c0 + cc) * WIN * WIN + gy * WIN + gx];
            ls_in[cc][r][xx + ((xx >> 4) << 2)] = v;
        }
        const float* wsrc = wT + (size_t)c0 * 16 * WOC + oc_base;
        for (int i = tid; i < CC * 16 * COUT; i += 256) {
            int o = i % COUT; int tt = (i / COUT) % 16; int cc = i / (16 * COUT);
            ls_w[cc][tt][o] = wsrc[(cc * 16 + tt) * WOC + o];
        }
        __syncthreads();

        for (int cc = 0; cc < CC; ++cc) {
            const float* lw = &ls_w[cc][0][0];
            #pragma unroll
            for (int ky = 0; ky < 4; ++ky) {
                float rv[18];
                const float* base = &ls_in[cc][ky][20 * pxg];
                #pragma unroll
                for (int q = 0; q < 4; ++q) {
                    float4 v = *reinterpret_cast<const float4*>(base + 4 * q);
                    rv[4*q]=v.x; rv[4*q+1]=v.y; rv[4*q+2]=v.z; rv[4*q+3]=v.w;
                }
                rv[16] = base[20]; rv[17] = base[21];
                #pragma unroll
                for (int kx = 0; kx < 4; ++kx) {
                    const float* wp = lw + (ky * 4 + kx) * COUT + oc0;
                    float wv[OCB];
                    if constexpr (OCB == 4) {
                        float4 w4 = *reinterpret_cast<const float4*>(wp);
                        wv[0]=w4.x; wv[1]=w4.y; wv[2]=w4.z; wv[3]=w4.w;
                    } else {
                        float2 w2 = *reinterpret_cast<const float2*>(wp);
                        wv[0]=w2.x; wv[1]=w2.y;
                    }
                    #pragma unroll
                    for (int p = 0; p < 8; ++p) {
                        float iv = rv[2 * p + kx];
                        #pragma unroll
                        for (int o = 0; o < OCB; ++o)
                            acc[o][p] = fmaf(iv, wv[o], acc[o][p]);
                    }
                }
            }
        }
    }
    #pragma unroll
    for (int o = 0; o < OCB; ++o) {
        float* op = out + (((size_t)b * (COUT * NSLICE) + oc_base + oc0 + o) * WOUT + y) * WOUT + x0;
        #pragma unroll
        for (int q = 0; q < 2; ++q) {
            float4 v = make_float4(fmaxf(acc[o][4*q],0.f), fmaxf(acc[o][4*q+1],0.f),
                                   fmaxf(acc[o][4*q+2],0.f), fmaxf(acc[o][4*q+3],0.f));
            *reinterpret_cast<float4*>(op + 4 * q) = v;
        }
    }
}

// ---------------- MFMA upconv: bilinear-2x(align) + conv3x3 64->3 + sigmoid -
__global__ __launch_bounds__(512) void upconv_mfma(
    const float* __restrict__ in,            // [8,64,128,128] post-relu
    const unsigned short* __restrict__ whi,
    const unsigned short* __restrict__ wlo,
    float* __restrict__ out)                 // [8,3,256,256]
{
    constexpr int CST = 24;
    __shared__ unsigned short ls_hi[6 * 68 * CST];
    __shared__ unsigned short ls_lo[6 * 68 * CST];
    __shared__ float xfx[68];
    __shared__ int   xloT[68];

    int tid = threadIdx.x;
    int lane = tid & 63;
    int w = tid >> 6;
    int myrow = w & 3;                 // output row within block
    int pt = w >> 2;                   // px tile: 0/1 -> px base pt*32
    int blk = blockIdx.x;
    int xq = blk & 3;
    int yblk = (blk >> 2) & 63;
    int b = blk >> 8;
    int xbase = xq * 64;
    int y0 = yblk * 4;
    int ln31 = lane & 31;
    int lhf = lane >> 5;
    const float SCL = 127.0f / 255.0f;
    const float* hb = in + (size_t)b * 64 * 16384;

    if (tid < 68) {
        int ux = xbase - 1 + tid;
        bool v = ((unsigned)ux < 256u);
        float px = (v ? ux : 0) * SCL;
        int lo = (int)px;
        xloT[tid] = lo;
        xfx[tid] = v ? (px - (float)lo) : -1.0f;   // -1 marks OOB
    }

    f32x16 acc = {};

    for (int chunk = 0; chunk < 4; ++chunk) {
        int c0 = chunk * 16;
        __syncthreads();
        for (int i = tid; i < 6 * 68 * 8; i += 512) {
            int xx = i % 68; int t = i / 68; int cp = t & 7; int r = t >> 3;
            int uy = y0 - 1 + r;
            float v0 = 0.f, v1 = 0.f;
            float fx = xfx[xx];
            if ((unsigned)uy < 256u && fx >= 0.f) {
                float py = uy * SCL;
                int ylo = (int)py; int yhi = min(ylo + 1, 127);
                float fy = py - (float)ylo;
                int lo = xloT[xx]; int hi = min(lo + 1, 127);
                const float* hp = hb + (size_t)(c0 + 2 * cp) * 16384;
                const float* p0 = hp + ylo * 128;
                const float* p1 = hp + yhi * 128;
                float a = p0[lo], b2 = p0[hi], c2 = p1[lo], d2 = p1[hi];
                float top = a + (b2 - a) * fx;
                float bot = c2 + (d2 - c2) * fx;
                v0 = top + (bot - top) * fy;
                const float* q0 = p0 + 16384;
                const float* q1 = p1 + 16384;
                float a2 = q0[lo], b3 = q0[hi], c3 = q1[lo], d3 = q1[hi];
                float top2 = a2 + (b3 - a2) * fx;
                float bot2 = c3 + (d3 - c3) * fx;
                v1 = top2 + (bot2 - top2) * fy;
            }
            unsigned short h0 = f2bf(v0), h1 = f2bf(v1);
            unsigned short l0 = f2bf(v0 - bf2f(h0)), l1 = f2bf(v1 - bf2f(h1));
            int a = (r * 68 + xx) * CST + 2 * cp;
            *reinterpret_cast<unsigned int*>(&ls_hi[a]) = (unsigned)h0 | ((unsigned)h1 << 16);
            *reinterpret_cast<unsigned int*>(&ls_lo[a]) = (unsigned)l0 | ((unsigned)l1 << 16);
        }
        __syncthreads();

        #pragma unroll
        for (int tap = 0; tap < 9; ++tap) {
            int dy = tap / 3, dx = tap - 3 * (tap / 3);
            size_t aoff = ((size_t)((tap * 4 + chunk) * 32 + ln31)) * 16 + lhf * 8;
            short8v ah = *reinterpret_cast<const short8v*>(whi + aoff);
            short8v al = *reinterpret_cast<const short8v*>(wlo + aoff);
            int boff = ((myrow + dy) * 68 + pt * 32 + ln31 + dx) * CST + lhf * 8;
            short8v bh = *reinterpret_cast<const short8v*>(&ls_hi[boff]);
            short8v bl = *reinterpret_cast<const short8v*>(&ls_lo[boff]);
            acc = __builtin_amdgcn_mfma_f32_32x32x16_bf16(ah, bh, acc, 0, 0, 0);
            acc = __builtin_amdgcn_mfma_f32_32x32x16_bf16(ah, bl, acc, 0, 0, 0);
            acc = __builtin_amdgcn_mfma_f32_32x32x16_bf16(al, bh, acc, 0, 0, 0);
        }
    }

    if (lhf == 0) {
        int y = y0 + myrow;
        int x0 = xbase + pt * 32 + ln31;
        #pragma unroll
        for (int r = 0; r < 3; ++r) {
            float v = 2.f / (1.f + expf(-acc[r])) - 1.f;
            out[(((size_t)b * 3 + r) * 256 + y) * 256 + x0] = v;
        }
    }
}

// ---------------- codebook prep: bf16 hi/lo frag pack + ce2 + zero counts --
__global__ void prep_codebook(const float* __restrict__ cb,
                              unsigned short* __restrict__ cbh,
                              unsigned short* __restrict__ cbl,
                              float* __restrict__ ce2,
                              unsigned int* __restrict__ counts)
{
    int k = blockIdx.x * 256 + threadIdx.x;
    if (k >= 1024) return;
    float s = 0.f;
    for (int d = 0; d < 128; ++d) {
        float v = cb[k * 128 + d];
        s = fmaf(v, v, s);
        unsigned short h = f2bf(v);
        int kk = d >> 4, t = d & 15;
        cbh[(kk * 1024 + k) * 16 + t] = h;
        cbl[(kk * 1024 + k) * 16 + t] = f2bf(v - bf2f(h));
    }
    ce2[k] = s;
    counts[k] = 0u;
}

// ---------------- VQ part A: MFMA distances + argmin -> gidx (no atomics) --
__global__ __launch_bounds__(512) void vq_dist_k(
    const float* __restrict__ z,
    const unsigned short* __restrict__ cbh,
    const unsigned short* __restrict__ cbl,
    const float* __restrict__ ce2,
    int* __restrict__ gidx)
{
    __shared__ unsigned short zfh_l[2][8][64][8];   // [pxg][kk][lane][j] hi
    __shared__ unsigned short zfl_l[2][8][64][8];   // lo
    __shared__ float ce2l[1024];
    __shared__ float cmbd[8][64];
    __shared__ int   cmbi[8][64];

    int tid = threadIdx.x;
    int lane = tid & 63;
    int w = tid >> 6;                  // wave = code group (128 codes)
    int ln31 = lane & 31;
    int lhf = lane >> 5;
    int p0g = blockIdx.x * 64;
    int b = p0g >> 12;
    int p0 = p0g & 4095;

    for (int i = tid; i < 8192; i += 512) {
        int d = i >> 6, px = i & 63;
        float v = z[((size_t)b * 128 + d) * 4096 + p0 + px];
        unsigned short h = f2bf(v);
        int kk = d >> 4;
        int lhf2 = (d >> 3) & 1;
        int j = d & 7;
        int lane2 = lhf2 * 32 + (px & 31);
        int pxg2 = px >> 5;
        zfh_l[pxg2][kk][lane2][j] = h;
        zfl_l[pxg2][kk][lane2][j] = f2bf(v - bf2f(h));
    }
    for (int i = tid; i < 1024; i += 512) ce2l[i] = ce2[i];
    __syncthreads();

    const unsigned short* zh0 = &zfh_l[0][0][lane][0];   // kk stride 512 shorts
    const unsigned short* zl0 = &zfl_l[0][0][lane][0];
    const unsigned short* zh1 = &zfh_l[1][0][lane][0];
    const unsigned short* zl1 = &zfl_l[1][0][lane][0];

    float best0 = 3.4e38f, best1 = 3.4e38f;
    int bidx0 = 0, bidx1 = 0;

    for (int ct = 0; ct < 4; ++ct) {
        int c0 = w * 128 + ct * 32;
        f32x16 acc0 = {};
        f32x16 acc1 = {};
        #pragma unroll
        for (int kk = 0; kk < 8; ++kk) {
            size_t ao = ((size_t)(kk * 1024 + c0 + ln31)) * 16 + lhf * 8;
            short8v ah = *reinterpret_cast<const short8v*>(cbh + ao);
            short8v al = *reinterpret_cast<const short8v*>(cbl + ao);
            short8v bh0 = *reinterpret_cast<const short8v*>(zh0 + kk * 512);
            short8v bl0 = *reinterpret_cast<const short8v*>(zl0 + kk * 512);
            short8v bh1 = *reinterpret_cast<const short8v*>(zh1 + kk * 512);
            short8v bl1 = *reinterpret_cast<const short8v*>(zl1 + kk * 512);
            acc0 = __builtin_amdgcn_mfma_f32_32x32x16_bf16(ah, bh0, acc0, 0, 0, 0);
            acc1 = __builtin_amdgcn_mfma_f32_32x32x16_bf16(ah, bh1, acc1, 0, 0, 0);
            acc0 = __builtin_amdgcn_mfma_f32_32x32x16_bf16(ah, bl0, acc0, 0, 0, 0);
            acc1 = __builtin_amdgcn_mfma_f32_32x32x16_bf16(ah, bl1, acc1, 0, 0, 0);
            acc0 = __builtin_amdgcn_mfma_f32_32x32x16_bf16(al, bh0, acc0, 0, 0, 0);
            acc1 = __builtin_amdgcn_mfma_f32_32x32x16_bf16(al, bh1, acc1, 0, 0, 0);
        }
        #pragma unroll
        for (int r = 0; r < 16; ++r) {
            int code = c0 + (r & 3) + 8 * (r >> 2) + 4 * lhf;
            float ce = ce2l[code];
            float d0 = ce - 2.f * acc0[r];
            float d1 = ce - 2.f * acc1[r];
            if (d0 < best0 || (d0 == best0 && code < bidx0)) { best0 = d0; bidx0 = code; }
            if (d1 < best1 || (d1 == best1 && code < bidx1)) { best1 = d1; bidx1 = code; }
        }
    }

    {
        float ob = __shfl_xor(best0, 32);
        int   oi = __shfl_xor(bidx0, 32);
        if (ob < best0 || (ob == best0 && oi < bidx0)) { best0 = ob; bidx0 = oi; }
        ob = __shfl_xor(best1, 32);
        oi = __shfl_xor(bidx1, 32);
        if (ob < best1 || (ob == best1 && oi < bidx1)) { best1 = ob; bidx1 = oi; }
    }
    if (lane < 32) {
        cmbd[w][ln31] = best0;      cmbi[w][ln31] = bidx0;
        cmbd[w][32 + ln31] = best1; cmbi[w][32 + ln31] = bidx1;
    }
    __syncthreads();
    if (tid < 64) {
        float bv = cmbd[0][tid]; int bi = cmbi[0][tid];
        #pragma unroll
        for (int g = 1; g < 8; ++g) {
            float ov = cmbd[g][tid]; int oi = cmbi[g][tid];
            if (ov < bv || (ov == bv && oi < bi)) { bv = ov; bi = oi; }
        }
        gidx[p0g + tid] = bi;
    }
}

// ---------------- VQ histogram: LDS-privatized, low-contention -------------
__global__ __launch_bounds__(256) void vq_hist_k(
    const int* __restrict__ gidx, unsigned int* __restrict__ counts)
{
    __shared__ unsigned int hc[1024];
    int tid = threadIdx.x;
    for (int i = tid; i < 1024; i += 256) hc[i] = 0u;
    __syncthreads();
    int base = blockIdx.x * 512;
    for (int i = tid; i < 512; i += 256)
        atomicAdd(&hc[gidx[base + i]], 1u);
    __syncthreads();
    for (int i = tid; i < 1024; i += 256) {
        unsigned int c = hc[i];
        if (c) atomicAdd(&counts[i], c);
    }
}

// ---------------- VQ part B: gather codebook rows, write q, loss partials --
__global__ __launch_bounds__(512) void vq_gather_k(
    const float* __restrict__ z, const float* __restrict__ cb,
    const int* __restrict__ gidx, float* __restrict__ q,
    double* __restrict__ partial)
{
    __shared__ float red[8];
    int tid = threadIdx.x;
    int lane = tid & 63;
    int w = tid >> 6;
    int p0g = blockIdx.x * 64;
    int b = p0g >> 12;
    int p0 = p0g & 4095;

    int pix = tid & 63, dg = tid >> 6;
    int kidx = gidx[p0g + pix];
    const float* crow = cb + (size_t)kidx * 128 + dg * 16;
    float sq = 0.f;
    size_t zbase = ((size_t)b * 128 + dg * 16) * 4096 + p0 + pix;
    #pragma unroll
    for (int ii = 0; ii < 4; ++ii) {
        float4 c4 = *reinterpret_cast<const float4*>(crow + 4 * ii);
        float vals[4] = {c4.x, c4.y, c4.z, c4.w};
        #pragma unroll
        for (int jj = 0; jj < 4; ++jj) {
            int dl = ii * 4 + jj;
            float qv = vals[jj];
            float zv = z[zbase + (size_t)dl * 4096];
            float df = qv - zv;
            sq = fmaf(df, df, sq);
            q[zbase + (size_t)dl * 4096] = qv;
        }
    }
    #pragma unroll
    for (int off = 32; off > 0; off >>= 1) sq += __shfl_xor(sq, off);
    if (lane == 0) red[w] = sq;
    __syncthreads();
    if (tid == 0) {
        double s = 0.0;
        #pragma unroll
        for (int ww = 0; ww < 8; ++ww) s += (double)red[ww];
        partial[blockIdx.x] = s;
    }
}

// ---------------- finalize ----------------
__global__ __launch_bounds__(256) void finalize_kernel(
    const double* __restrict__ partial, const unsigned int* __restrict__ counts,
    float* __restrict__ dout)
{
    __shared__ double sd[256];
    __shared__ double lossSh;
    int tid = threadIdx.x;
    double s = 0.0;
    for (int i = tid; i < 512; i += 256) s += partial[i];
    sd[tid] = s; __syncthreads();
    for (int off = 128; off > 0; off >>= 1) {
        if (tid < off) sd[tid] += sd[tid + off];
        __syncthreads();
    }
    if (tid == 0) lossSh = CC_COST * sd[0] / 4194304.0;
    __syncthreads();

    double h = 0.0;
    for (int k = tid; k < 1024; k += 256) {
        double pp = (double)counts[k] / 32768.0;
        h += pp * log(pp + 1e-10);
    }
    sd[tid] = h; __syncthreads();
    for (int off = 128; off > 0; off >>= 1) {
        if (tid < off) sd[tid] += sd[tid + off];
        __syncthreads();
    }
    if (tid == 0) {
        dout[0]       = (float)lossSh;
        dout[1572865] = (float)exp(-sd[0]);
    }
}

// ===========================================================================
extern "C" void kernel_launch(void* const* d_in, const int* in_sizes, int n_in,
                              void* d_out, int out_size, void* d_ws, size_t ws_size,
                              hipStream_t stream)
{
    const float* x        = (const float*)d_in[0];
    const float* enc_c1   = (const float*)d_in[1];
    const float* enc_c2   = (const float*)d_in[2];
    const float* enc_c3   = (const float*)d_in[3];
    const float* enc_r1a  = (const float*)d_in[4];
    const float* enc_r1b  = (const float*)d_in[5];
    const float* enc_r2a  = (const float*)d_in[6];
    const float* enc_r2b  = (const float*)d_in[7];
    const float* pre_vq_w = (const float*)d_in[8];
    const float* codebook = (const float*)d_in[9];
    const float* dec_c1   = (const float*)d_in[10];
    const float* dec_r1a  = (const float*)d_in[11];
    const float* dec_r1b  = (const float*)d_in[12];
    const float* dec_r2a  = (const float*)d_in[13];
    const float* dec_r2b  = (const float*)d_in[14];
    const float* dec_dc   = (const float*)d_in[15];
    const float* dec_c3   = (const float*)d_in[16];
    float* dout = (float*)d_out;

    char* wsp = (char*)d_ws;
    auto alloc = [&](size_t bytes) {
        void* p = (void*)wsp;
        wsp += (bytes + 255) & ~(size_t)255;
        return p;
    };
    float* h1   = (float*)alloc(8ull*64*128*128*4);   // 32MB; also qb alias
    float* bufA = (float*)alloc(8ull*128*64*64*4);    // 16MB; also zb alias
    float* bufB = (float*)alloc(8ull*128*64*64*4);    // 16MB
    unsigned short* cbh = (unsigned short*)alloc(131072*2);  // [8][1024][16]
    unsigned short* cbl = (unsigned short*)alloc(131072*2);
    float* ce2  = (float*)alloc(1024*4);
    unsigned int* counts = (unsigned int*)alloc(1024*4);
    double* partial = (double*)alloc(512*8);
    int* gidx = (int*)alloc(32768*4);
    float* wt_ec1  = (float*)alloc(3072*4);
    float* wt_pvq  = (float*)alloc(16384*4);
    unsigned short* w3hi_e = (unsigned short*)alloc(147456*2);
    unsigned short* w3lo_e = (unsigned short*)alloc(147456*2);
    unsigned short* w3hi_d = (unsigned short*)alloc(147456*2);
    unsigned short* w3lo_d = (unsigned short*)alloc(147456*2);
    unsigned short* w4hi   = (unsigned short*)alloc(131072*2);
    unsigned short* w4lo   = (unsigned short*)alloc(131072*2);
    unsigned short* wdchi  = (unsigned short*)alloc(131072*2);
    unsigned short* wdclo  = (unsigned short*)alloc(131072*2);
    unsigned short* wr1aeh = (unsigned short*)alloc(36864*2);
    unsigned short* wr1ael = (unsigned short*)alloc(36864*2);
    unsigned short* wr2aeh = (unsigned short*)alloc(36864*2);
    unsigned short* wr2ael = (unsigned short*)alloc(36864*2);
    unsigned short* wr1adh = (unsigned short*)alloc(36864*2);
    unsigned short* wr1adl = (unsigned short*)alloc(36864*2);
    unsigned short* wr2adh = (unsigned short*)alloc(36864*2);
    unsigned short* wr2adl = (unsigned short*)alloc(36864*2);
    unsigned short* w1e1h  = (unsigned short*)alloc(4096*2);
    unsigned short* w1e1l  = (unsigned short*)alloc(4096*2);
    unsigned short* w1e2h  = (unsigned short*)alloc(4096*2);
    unsigned short* w1e2l  = (unsigned short*)alloc(4096*2);
    unsigned short* w1d1h  = (unsigned short*)alloc(4096*2);
    unsigned short* w1d1l  = (unsigned short*)alloc(4096*2);
    unsigned short* w1d2h  = (unsigned short*)alloc(4096*2);
    unsigned short* w1d2l  = (unsigned short*)alloc(4096*2);
    unsigned short* wuph   = (unsigned short*)alloc(18432*2);
    unsigned short* wupl   = (unsigned short*)alloc(18432*2);
    float* zb = bufA;   // alias: pre_vq out (reads bufB), dead before dec writes bufA
    float* qb = h1;     // alias: dead before deconv overwrites h1

    // VQ prep: bf16 frag pack + ce2 + zero counts
    prep_codebook<<<4, 256, 0, stream>>>(codebook, cbh, cbl, ce2, counts);

    // batched weight transforms (2 fp32 jobs; MFMA layers use split kernels)
    WtJobs J;
    const float* srcs[2] = {enc_c1, pre_vq_w};
    float* dsts[2] = {wt_ec1, wt_pvq};
    int couts[2] = {64, 128};
    int cins[2]  = {3, 128};
    int kks[2]   = {16, 1};
    int kinds[2] = {0, 0};
    int off = 0;
    for (int j = 0; j < 2; ++j) {
        J.src[j] = srcs[j]; J.dst[j] = dsts[j];
        J.cout[j] = couts[j]; J.cin[j] = cins[j]; J.kk[j] = kks[j];
        J.kind[j] = kinds[j];
        J.blk0[j] = off;
        off += (couts[j] * cins[j] * kks[j] + 255) / 256;
    }
    J.blk0[2] = off;
    for (int j = 3; j < 16; ++j) J.blk0[j] = off + 1000000;  // sentinels
    wt_batch_k<<<off, 256, 0, stream>>>(J);
    wt_split_k<<<576, 256, 0, stream>>>(enc_c3, w3hi_e, w3lo_e);
    wt_split_k<<<576, 256, 0, stream>>>(dec_c1, w3hi_d, w3lo_d);
    wt_split4_k<<<512, 256, 0, stream>>>(enc_c2, w4hi, w4lo);
    wt_split_dc_k<<<512, 256, 0, stream>>>(dec_dc, wdchi, wdclo);
    wt_split_r_k<<<144, 256, 0, stream>>>(enc_r1a, wr1aeh, wr1ael);
    wt_split_r_k<<<144, 256, 0, stream>>>(enc_r2a, wr2aeh, wr2ael);
    wt_split_r_k<<<144, 256, 0, stream>>>(dec_r1a, wr1adh, wr1adl);
    wt_split_r_k<<<144, 256, 0, stream>>>(dec_r2a, wr2adh, wr2adl);
    wt_split_1x1_k<<<16, 256, 0, stream>>>(enc_r1b, w1e1h, w1e1l);
    wt_split_1x1_k<<<16, 256, 0, stream>>>(enc_r2b, w1e2h, w1e2l);
    wt_split_1x1_k<<<16, 256, 0, stream>>>(dec_r1b, w1d1h, w1d1l);
    wt_split_1x1_k<<<16, 256, 0, stream>>>(dec_r2b, w1d2h, w1d2l);
    wt_split_up_k<<<72, 256, 0, stream>>>(dec_c3, wuph, wupl);

    // ---- encoder ----
    conv4x4s2_k<3, 64, 128, 3, 4, 64, 1><<<1024, 256, 0, stream>>>(x, wt_ec1, h1);
    conv4x4s2_mfma<<<256, 512, 0, stream>>>(h1, w4hi, w4lo, bufA);
    conv3x3_mfma<<<256, 512, 0, stream>>>(bufA, w3hi_e, w3lo_e, bufB);
    fused_res_k<<<512, 512, 0, stream>>>(bufB, wr1aeh, wr1ael, w1e1h, w1e1l, bufA);
    fused_res_k<<<512, 512, 0, stream>>>(bufA, wr2aeh, wr2ael, w1e2h, w1e2l, bufB);
    conv1x1_k<128, 128, 32, true, false><<<512, 256, 0, stream>>>(bufB, wt_pvq, bufB, zb);

    // ---- VQ: dist+argmin (no atomics), histogram, gather/q/loss ----
    vq_dist_k<<<512, 512, 0, stream>>>(zb, cbh, cbl, ce2, gidx);
    vq_hist_k<<<64, 256, 0, stream>>>(gidx, counts);
    vq_gather_k<<<512, 512, 0, stream>>>(zb, codebook, gidx, qb, partial);

    // ---- decoder ----
    conv3x3_mfma<<<256, 512, 0, stream>>>(qb, w3hi_d, w3lo_d, bufA);
    fused_res_k<<<512, 512, 0, stream>>>(bufA, wr1adh, wr1adl, w1d1h, w1d1l, bufB);
    fused_res_k<<<512, 512, 0, stream>>>(bufB, wr2adh, wr2adl, w1d2h, w1d2l, bufA);
    deconv_mfma<<<512, 512, 0, stream>>>(bufA, wdchi, wdclo, h1);
    upconv_mfma<<<2048, 512, 0, stream>>>(h1, wuph, wupl, dout + 1);

    // ---- scalars ----
    finalize_kernel<<<1, 256, 0, stream>>>(partial, counts, dout);
}